// Round 10
// baseline (511.994 us; speedup 1.0000x reference)
//
#include <hip/hip_runtime.h>
#include <math.h>

#define N_NODES 100000
#define N_EDGES 1600000
#define DIM     128
#define NCLS    40
#define SCAN_BLOCKS 98   // ceil(100000/1024)
#define NBUCK   196      // ceil(100000/512) buckets of 512 nodes
#define P1_CH   4096     // edges per phase-1 block
#define P1_GRID 391      // ceil(1600000/4096)

typedef _Float16 f16x8 __attribute__((ext_vector_type(8)));
typedef _Float16 f16x2 __attribute__((ext_vector_type(2)));
typedef float    f32x4 __attribute__((ext_vector_type(4)));

__device__ inline unsigned short f16bits(float f) {
    union { _Float16 h; unsigned short u; } cv;
    cv.h = (_Float16)f;
    return cv.u;
}
__device__ inline f16x2 as_h2(unsigned u) {
    union { unsigned u; f16x2 h; } cv;
    cv.u = u;
    return cv.h;
}
__device__ inline unsigned as_u(f16x2 h) {
    union { f16x2 h; unsigned u; } cv;
    cv.h = h;
    return cv.u;
}
__device__ inline unsigned pack_h2(float lo, float hi) {
    f16x2 h;
    h.x = (_Float16)lo;
    h.y = (_Float16)hi;
    return as_u(h);
}

// ---------------------------------------------------------------- degree (int)
__global__ __launch_bounds__(256) void deg_count(const int* __restrict__ ei,
                                                 int* __restrict__ degi) {
    int e = blockIdx.x * 256 + threadIdx.x;
    if (e < N_EDGES) atomicAdd(&degi[ei[N_EDGES + e]], 1);
}

__global__ __launch_bounds__(256) void finalize_dinv(const int* __restrict__ degi,
                                                     float* __restrict__ dinv) {
    int n = blockIdx.x * 256 + threadIdx.x;
    if (n < N_NODES) dinv[n] = rsqrtf((float)degi[n] + 1.0f);
}

// ---------------------------------------------------------------- scan (exclusive) over degi -> rowptr
__global__ __launch_bounds__(256) void scan1(const int* __restrict__ degi,
                                             int* __restrict__ rowptr,
                                             int* __restrict__ bsums) {
    __shared__ int sums[256];
    int t    = threadIdx.x;
    int base = blockIdx.x * 1024 + t * 4;
    int v[4], s = 0;
#pragma unroll
    for (int i = 0; i < 4; ++i) {
        int idx = base + i;
        v[i] = (idx < N_NODES) ? degi[idx] : 0;
        s += v[i];
    }
    sums[t] = s;
    __syncthreads();
    for (int off = 1; off < 256; off <<= 1) {
        int x = (t >= off) ? sums[t - off] : 0;
        __syncthreads();
        sums[t] += x;
        __syncthreads();
    }
    int run = (t == 0) ? 0 : sums[t - 1];
#pragma unroll
    for (int i = 0; i < 4; ++i) {
        int idx = base + i;
        if (idx < N_NODES) rowptr[idx] = run;
        run += v[i];
    }
    if (t == 255) bsums[blockIdx.x] = sums[255];
}

__global__ __launch_bounds__(128) void scan2(int* __restrict__ bsums) {
    __shared__ int s[128];
    int t = threadIdx.x;
    s[t] = (t < SCAN_BLOCKS) ? bsums[t] : 0;
    __syncthreads();
    for (int off = 1; off < 128; off <<= 1) {
        int x = (t >= off) ? s[t - off] : 0;
        __syncthreads();
        s[t] += x;
        __syncthreads();
    }
    if (t < SCAN_BLOCKS) bsums[t] = (t == 0) ? 0 : s[t - 1];
}

__global__ __launch_bounds__(256) void scan3(int* __restrict__ rowptr,
                                             int* __restrict__ bcur,
                                             const int* __restrict__ bsums) {
    int idx = blockIdx.x * 256 + threadIdx.x;
    if (idx < N_NODES) {
        int v = rowptr[idx] + bsums[idx >> 10];
        rowptr[idx] = v;
        if ((idx & 511) == 0) bcur[idx >> 9] = v;   // bucket base cursor
    }
    if (idx == 0) rowptr[N_NODES] = N_EDGES;
}

// ---------------------------------------------------------------- phase 1: bucket edges by dst>>9 into tmp (coalesced runs)
__global__ __launch_bounds__(256) void bucket_p1(const int* __restrict__ ei,
                                                 int* __restrict__ bcur,
                                                 int2* __restrict__ tmp) {
    __shared__ int  hist[256];
    __shared__ int  lscan[256];
    __shared__ int  rank[256];
    __shared__ int  gbase[256];
    __shared__ int2 stage[P1_CH];      // 32 KB
    const int t  = threadIdx.x;
    const int e0 = blockIdx.x * P1_CH;
    const int cnt = min(P1_CH, N_EDGES - e0);

    hist[t] = 0;
    __syncthreads();

    int2 ed[16];
#pragma unroll
    for (int i = 0; i < 16; ++i) {
        int idx = t + i * 256;
        if (idx < cnt) {
            int s = ei[e0 + idx];
            int d = ei[N_EDGES + e0 + idx];
            ed[i] = make_int2(s, d);
            atomicAdd(&hist[d >> 9], 1);
        }
    }
    __syncthreads();

    int hv = hist[t];
    lscan[t] = hv;
    __syncthreads();
    for (int off = 1; off < 256; off <<= 1) {
        int x = (t >= off) ? lscan[t - off] : 0;
        __syncthreads();
        lscan[t] += x;
        __syncthreads();
    }
    int excl = (t == 0) ? 0 : lscan[t - 1];
    __syncthreads();
    lscan[t] = excl;
    rank[t]  = excl;
    if (hv > 0) gbase[t] = atomicAdd(&bcur[t], hv);
    __syncthreads();

#pragma unroll
    for (int i = 0; i < 16; ++i) {
        int idx = t + i * 256;
        if (idx < cnt) {
            int b = ed[i].y >> 9;
            int p = atomicAdd(&rank[b], 1);
            stage[p] = ed[i];
        }
    }
    __syncthreads();

    for (int p = t; p < cnt; p += 256) {
        int2 v = stage[p];
        int b = v.y >> 9;
        tmp[gbase[b] + (p - lscan[b])] = v;
    }
}

// ---------------------------------------------------------------- phase 2: within-bucket scatter; weight packed as half2 (w,w)
__global__ __launch_bounds__(256) void bucket_p2(const int2* __restrict__ tmp,
                                                 const int* __restrict__ rowptr,
                                                 const float* __restrict__ dinv,
                                                 int2* __restrict__ rec) {
    __shared__ int cur[512];
    const int t  = threadIdx.x;
    const int b  = blockIdx.x;
    const int d0 = b << 9;
    const int dend = min(d0 + 512, N_NODES);
    const int nn = dend - d0;

    for (int i = t; i < nn; i += 256) cur[i] = rowptr[d0 + i];
    __syncthreads();

    const int beg = rowptr[d0];
    const int end = rowptr[dend];
    for (int idx = beg + t; idx < end; idx += 256) {
        int2 v = tmp[idx];
        int s = v.x, d = v.y;
        int pos = atomicAdd(&cur[d - d0], 1);
        unsigned short wb = f16bits(dinv[s] * dinv[d]);
        rec[pos] = make_int2(s, (int)((unsigned)wb | ((unsigned)wb << 16)));
    }
}

// ---------------------------------------------------------------- W pre-swizzle into MFMA B-fragment order (f16)
__global__ __launch_bounds__(256) void wswz(const float* __restrict__ W,
                                            unsigned short* __restrict__ Wsw) {
    int o = blockIdx.x * 256 + threadIdx.x;      // 0..16383
    int f = o >> 9;
    int l = (o >> 3) & 63;
    int j = o & 7;
    int n = f >> 2;
    int s = f & 3;
    int k = s * 32 + (l >> 4) * 8 + j;
    int c = (l & 15) * 8 + n;
    Wsw[o] = f16bits(W[k * DIM + c]);
}

// ---------------------------------------------------------------- Wc pre-swizzle (128x40 -> 3 n-tiles, c = 3m+n), f16
__global__ __launch_bounds__(256) void wcswz(const float* __restrict__ Wc,
                                             unsigned short* __restrict__ Wcsw) {
    int o = blockIdx.x * 256 + threadIdx.x;      // 0..6143
    if (o >= 12 * 512) return;
    int f = o >> 9;
    int l = (o >> 3) & 63;
    int j = o & 7;
    int n = f >> 2;
    int s = f & 3;
    int k = s * 32 + (l >> 4) * 8 + j;
    int c = (l & 15) * 3 + n;
    Wcsw[o] = (c < NCLS) ? f16bits(Wc[k * NCLS + c]) : (unsigned short)0;
}

// ---------------------------------------------------------------- MFMA GEMM, fp32 input (layer 0): H(f16) = X @ W
__global__ __launch_bounds__(256, 2) void gemm_mfma_f(const float* __restrict__ X,
                                                      const unsigned short* __restrict__ Wsw,
                                                      unsigned short* __restrict__ H) {
    const int lane  = threadIdx.x & 63;
    const int wave  = threadIdx.x >> 6;
    const int row0w = blockIdx.x * 64 + wave * 16;
    const int m = lane & 15;
    const int q = lane >> 4;

    f16x8 wf[32];
#pragma unroll
    for (int f = 0; f < 32; ++f)
        wf[f] = *(const f16x8*)(Wsw + (f << 9) + lane * 8);

    int r = row0w + m;
    if (r >= N_NODES) r = N_NODES - 1;
    const float* xp = X + (size_t)r * DIM + q * 8;
    f16x8 af[4];
#pragma unroll
    for (int s = 0; s < 4; ++s) {
        float4 x0 = *(const float4*)(xp + s * 32);
        float4 x1 = *(const float4*)(xp + s * 32 + 4);
        f16x8 v;
        v[0] = (_Float16)x0.x; v[1] = (_Float16)x0.y;
        v[2] = (_Float16)x0.z; v[3] = (_Float16)x0.w;
        v[4] = (_Float16)x1.x; v[5] = (_Float16)x1.y;
        v[6] = (_Float16)x1.z; v[7] = (_Float16)x1.w;
        af[s] = v;
    }

    f32x4 acc[8];
    f32x4 z = {0.f, 0.f, 0.f, 0.f};
#pragma unroll
    for (int n = 0; n < 8; ++n) acc[n] = z;

#pragma unroll
    for (int s = 0; s < 4; ++s)
#pragma unroll
        for (int n = 0; n < 8; ++n)
            acc[n] = __builtin_amdgcn_mfma_f32_16x16x32_f16(af[s], wf[n * 4 + s], acc[n], 0, 0, 0);

#pragma unroll
    for (int j = 0; j < 4; ++j) {
        int row = row0w + q * 4 + j;
        if (row < N_NODES) {
            uint4 o;
            o.x = pack_h2(acc[0][j], acc[1][j]);
            o.y = pack_h2(acc[2][j], acc[3][j]);
            o.z = pack_h2(acc[4][j], acc[5][j]);
            o.w = pack_h2(acc[6][j], acc[7][j]);
            *(uint4*)(H + (size_t)row * DIM + m * 8) = o;
        }
    }
}

// ---------------------------------------------------------------- MFMA GEMM, f16 input (layers 1,2)
__global__ __launch_bounds__(256, 2) void gemm_mfma_h(const unsigned short* __restrict__ Xh,
                                                      const unsigned short* __restrict__ Wsw,
                                                      unsigned short* __restrict__ H) {
    const int lane  = threadIdx.x & 63;
    const int wave  = threadIdx.x >> 6;
    const int row0w = blockIdx.x * 64 + wave * 16;
    const int m = lane & 15;
    const int q = lane >> 4;

    f16x8 wf[32];
#pragma unroll
    for (int f = 0; f < 32; ++f)
        wf[f] = *(const f16x8*)(Wsw + (f << 9) + lane * 8);

    int r = row0w + m;
    if (r >= N_NODES) r = N_NODES - 1;
    const unsigned short* xp = Xh + (size_t)r * DIM + q * 8;
    f16x8 af[4];
#pragma unroll
    for (int s = 0; s < 4; ++s) af[s] = *(const f16x8*)(xp + s * 32);

    f32x4 acc[8];
    f32x4 z = {0.f, 0.f, 0.f, 0.f};
#pragma unroll
    for (int n = 0; n < 8; ++n) acc[n] = z;

#pragma unroll
    for (int s = 0; s < 4; ++s)
#pragma unroll
        for (int n = 0; n < 8; ++n)
            acc[n] = __builtin_amdgcn_mfma_f32_16x16x32_f16(af[s], wf[n * 4 + s], acc[n], 0, 0, 0);

#pragma unroll
    for (int j = 0; j < 4; ++j) {
        int row = row0w + q * 4 + j;
        if (row < N_NODES) {
            uint4 o;
            o.x = pack_h2(acc[0][j], acc[1][j]);
            o.y = pack_h2(acc[2][j], acc[3][j]);
            o.z = pack_h2(acc[4][j], acc[5][j]);
            o.w = pack_h2(acc[6][j], acc[7][j]);
            *(uint4*)(H + (size_t)row * DIM + m * 8) = o;
        }
    }
}

// ---------------------------------------------------------------- fused gather-aggregate + LN + ELU (+ residual), f16
// One wave per node, quarter-split: qtr=lane>>4 handles every 4th edge;
// lane owns 8 cols (sub*8..+7). One dwordx4 wave-load serves 4 edges.
// Accumulate in packed f16 (v_pk_fma_f16), merge quarters via shfl_xor.
__global__ __launch_bounds__(256) void agg_ln(const unsigned short* __restrict__ Hh,
                                              const unsigned short* __restrict__ xin,
                                              const float* __restrict__ dinv,
                                              const float* __restrict__ bias,
                                              const float* __restrict__ g,
                                              const float* __restrict__ be,
                                              const int* __restrict__ rowptr,
                                              const int2* __restrict__ rec,
                                              unsigned short* __restrict__ outb) {
    int node = blockIdx.x * 4 + (threadIdx.x >> 6);
    int lane = threadIdx.x & 63;
    int sub  = lane & 15;
    int qtr  = lane >> 4;
    int beg = rowptr[node];
    int end = rowptr[node + 1];

    f16x2 acc[4];
    f16x2 hz = {(_Float16)0.f, (_Float16)0.f};
#pragma unroll
    for (int k = 0; k < 4; ++k) acc[k] = hz;

    for (int e0 = beg; e0 < end; e0 += 64) {
        int cnt = min(end - e0, 64);
        int2 rc = (lane < cnt) ? rec[e0 + lane] : make_int2(0, 0);
        int sv = rc.x;
        int wv = rc.y;                        // packed half2 (w,w)
        int cntR = (cnt + 7) & ~7;
        for (int j = 0; j < cntR; j += 8) {
            int i0 = j + qtr, i1 = j + 4 + qtr;
            int s0 = __shfl(sv, i0, 64); int w0 = __shfl(wv, i0, 64);
            int s1 = __shfl(sv, i1, 64); int w1 = __shfl(wv, i1, 64);
            uint4 u0 = *(const uint4*)(Hh + (size_t)s0 * DIM + sub * 8);
            uint4 u1 = *(const uint4*)(Hh + (size_t)s1 * DIM + sub * 8);
            f16x2 hw0 = as_h2(w0), hw1 = as_h2(w1);
            acc[0] += as_h2(u0.x) * hw0;
            acc[1] += as_h2(u0.y) * hw0;
            acc[2] += as_h2(u0.z) * hw0;
            acc[3] += as_h2(u0.w) * hw0;
            acc[0] += as_h2(u1.x) * hw1;
            acc[1] += as_h2(u1.y) * hw1;
            acc[2] += as_h2(u1.z) * hw1;
            acc[3] += as_h2(u1.w) * hw1;
        }
    }

    // merge quarters (all 4 groups end with identical full col sums)
#pragma unroll
    for (int k = 0; k < 4; ++k) {
        acc[k] += as_h2(__shfl_xor(as_u(acc[k]), 16, 64));
        acc[k] += as_h2(__shfl_xor(as_u(acc[k]), 32, 64));
    }

    // to f32 + self-loop + bias
    float a[8];
#pragma unroll
    for (int k = 0; k < 4; ++k) {
        a[2 * k]     = (float)acc[k].x;
        a[2 * k + 1] = (float)acc[k].y;
    }
    float dv = dinv[node];
    float d2 = dv * dv;
    uint4 hv = *(const uint4*)(Hh + (size_t)node * DIM + sub * 8);
    float4 b0 = ((const float4*)bias)[sub * 2];
    float4 b1 = ((const float4*)bias)[sub * 2 + 1];
    {
        f16x2 h0 = as_h2(hv.x), h1 = as_h2(hv.y), h2 = as_h2(hv.z), h3 = as_h2(hv.w);
        a[0] += (float)h0.x * d2 + b0.x;
        a[1] += (float)h0.y * d2 + b0.y;
        a[2] += (float)h1.x * d2 + b0.z;
        a[3] += (float)h1.y * d2 + b0.w;
        a[4] += (float)h2.x * d2 + b1.x;
        a[5] += (float)h2.y * d2 + b1.y;
        a[6] += (float)h3.x * d2 + b1.z;
        a[7] += (float)h3.y * d2 + b1.w;
    }

    // LN stats across 16 lanes (each quarter-group identical)
    float s1 = 0.f, s2 = 0.f;
#pragma unroll
    for (int k = 0; k < 8; ++k) { s1 += a[k]; s2 += a[k] * a[k]; }
#pragma unroll
    for (int mk = 1; mk <= 8; mk <<= 1) {
        s1 += __shfl_xor(s1, mk, 64);
        s2 += __shfl_xor(s2, mk, 64);
    }
    float mean = s1 * (1.0f / 128.0f);
    float var  = s2 * (1.0f / 128.0f) - mean * mean;
    float rr   = rsqrtf(var + 1e-5f);
    float4 g0 = ((const float4*)g)[sub * 2];
    float4 g1 = ((const float4*)g)[sub * 2 + 1];
    float4 e0v = ((const float4*)be)[sub * 2];
    float4 e1v = ((const float4*)be)[sub * 2 + 1];
    float gv[8] = {g0.x, g0.y, g0.z, g0.w, g1.x, g1.y, g1.z, g1.w};
    float ev[8] = {e0v.x, e0v.y, e0v.z, e0v.w, e1v.x, e1v.y, e1v.z, e1v.w};
    float r[8];
#pragma unroll
    for (int k = 0; k < 8; ++k) {
        float t = (a[k] - mean) * rr * gv[k] + ev[k];
        r[k] = t > 0.0f ? t : expm1f(t);
    }
    if (xin) {
        uint4 xi = *(const uint4*)(xin + (size_t)node * DIM + sub * 8);
        f16x2 x0 = as_h2(xi.x), x1 = as_h2(xi.y), x2 = as_h2(xi.z), x3 = as_h2(xi.w);
        r[0] += (float)x0.x; r[1] += (float)x0.y;
        r[2] += (float)x1.x; r[3] += (float)x1.y;
        r[4] += (float)x2.x; r[5] += (float)x2.y;
        r[6] += (float)x3.x; r[7] += (float)x3.y;
    }
    if (qtr == 0) {
        uint4 o;
        o.x = pack_h2(r[0], r[1]);
        o.y = pack_h2(r[2], r[3]);
        o.z = pack_h2(r[4], r[5]);
        o.w = pack_h2(r[6], r[7]);
        *(uint4*)(outb + (size_t)node * DIM + sub * 8) = o;
    }
}

// ---------------------------------------------------------------- MFMA classifier, f16 input: out = X @ Wc + bc
__global__ __launch_bounds__(256) void classifier_mfma(const unsigned short* __restrict__ Xh,
                                                       const unsigned short* __restrict__ Wcsw,
                                                       const float* __restrict__ bc,
                                                       float* __restrict__ out) {
    const int lane  = threadIdx.x & 63;
    const int wave  = threadIdx.x >> 6;
    const int row0w = blockIdx.x * 64 + wave * 16;
    const int m = lane & 15;
    const int q = lane >> 4;

    f16x8 wf[12];
#pragma unroll
    for (int f = 0; f < 12; ++f)
        wf[f] = *(const f16x8*)(Wcsw + (f << 9) + lane * 8);

    int r = row0w + m;
    if (r >= N_NODES) r = N_NODES - 1;
    const unsigned short* xp = Xh + (size_t)r * DIM + q * 8;
    f16x8 af[4];
#pragma unroll
    for (int s = 0; s < 4; ++s) af[s] = *(const f16x8*)(xp + s * 32);

    f32x4 acc[3];
    f32x4 z = {0.f, 0.f, 0.f, 0.f};
#pragma unroll
    for (int n = 0; n < 3; ++n) acc[n] = z;

#pragma unroll
    for (int s = 0; s < 4; ++s)
#pragma unroll
        for (int n = 0; n < 3; ++n)
            acc[n] = __builtin_amdgcn_mfma_f32_16x16x32_f16(af[s], wf[n * 4 + s], acc[n], 0, 0, 0);

    float bcv[3];
#pragma unroll
    for (int n = 0; n < 3; ++n) {
        int c = 3 * m + n;
        bcv[n] = (c < NCLS) ? bc[c] : 0.f;
    }

#pragma unroll
    for (int j = 0; j < 4; ++j) {
        int row = row0w + q * 4 + j;
        if (row < N_NODES) {
#pragma unroll
            for (int n = 0; n < 3; ++n) {
                int c = 3 * m + n;
                if (c < NCLS)
                    out[(size_t)row * NCLS + c] = acc[n][j] + bcv[n];
            }
        }
    }
}

// ---------------------------------------------------------------- launch
extern "C" void kernel_launch(void* const* d_in, const int* in_sizes, int n_in,
                              void* d_out, int out_size, void* d_ws, size_t ws_size,
                              hipStream_t stream) {
    const float* x  = (const float*)d_in[0];
    const int*   ei = (const int*)d_in[1];
    const float* W[3]  = {(const float*)d_in[2], (const float*)d_in[6], (const float*)d_in[10]};
    const float* b[3]  = {(const float*)d_in[3], (const float*)d_in[7], (const float*)d_in[11]};
    const float* g[3]  = {(const float*)d_in[4], (const float*)d_in[8], (const float*)d_in[12]};
    const float* be[3] = {(const float*)d_in[5], (const float*)d_in[9], (const float*)d_in[13]};
    const float* Wc = (const float*)d_in[14];
    const float* bc = (const float*)d_in[15];
    float* out = (float*)d_out;

    char* ws = (char*)d_ws;
    const size_t NP = 400128;  // padded N*4 bytes
    float* dinv   = (float*)(ws);
    int*   degi   = (int*)  (ws + NP);
    int*   rowptr = (int*)  (ws + 2 * NP);
    int*   bcur   = (int*)  (ws + 3 * NP);
    int*   bsums  = (int*)  (ws + 4 * NP);
    int2*  rec    = (int2*) (ws + 4 * NP + 512);
    unsigned short* Hh = (unsigned short*)(ws + 4 * NP + 512 + (size_t)N_EDGES * 8);
    unsigned short* Ah = Hh + (size_t)N_NODES * DIM;
    unsigned short* Ch = Ah + (size_t)N_NODES * DIM;
    unsigned short* Wsw0 = Ch + (size_t)N_NODES * DIM;
    unsigned short* Wsw1 = Wsw0 + DIM * DIM;
    unsigned short* Wsw2 = Wsw1 + DIM * DIM;
    unsigned short* Wcsw = Wsw2 + DIM * DIM;   // 12*512 shorts
    int2*  tmp    = (int2*)Ch;                 // aliases Ch; dead before layer 0 writes Ch

    // ---- W pre-swizzles (f16, MFMA B-frag order) ----
    wswz<<<64, 256, 0, stream>>>(W[0], Wsw0);
    wswz<<<64, 256, 0, stream>>>(W[1], Wsw1);
    wswz<<<64, 256, 0, stream>>>(W[2], Wsw2);
    wcswz<<<24, 256, 0, stream>>>(Wc, Wcsw);

    // ---- CSR build ----
    hipMemsetAsync(degi, 0, N_NODES * sizeof(int), stream);
    deg_count<<<(N_EDGES + 255) / 256, 256, 0, stream>>>(ei, degi);
    finalize_dinv<<<(N_NODES + 255) / 256, 256, 0, stream>>>(degi, dinv);
    scan1<<<SCAN_BLOCKS, 256, 0, stream>>>(degi, rowptr, bsums);
    scan2<<<1, 128, 0, stream>>>(bsums);
    scan3<<<SCAN_BLOCKS * 4, 256, 0, stream>>>(rowptr, bcur, bsums);
    bucket_p1<<<P1_GRID, 256, 0, stream>>>(ei, bcur, tmp);
    bucket_p2<<<NBUCK, 256, 0, stream>>>(tmp, rowptr, dinv, rec);

    const int gemm_grid = (N_NODES + 63) / 64;    // 1563
    const int agg_grid  = N_NODES / 4;            // 25000

    // layer 0: x fp32 -> Hh; agg -> Ch
    gemm_mfma_f<<<gemm_grid, 256, 0, stream>>>(x, Wsw0, Hh);
    agg_ln<<<agg_grid, 256, 0, stream>>>(Hh, nullptr, dinv, b[0], g[0], be[0], rowptr, rec, Ch);

    // layer 1: Ch -> Hh; agg (+resid Ch) -> Ah
    gemm_mfma_h<<<gemm_grid, 256, 0, stream>>>(Ch, Wsw1, Hh);
    agg_ln<<<agg_grid, 256, 0, stream>>>(Hh, Ch, dinv, b[1], g[1], be[1], rowptr, rec, Ah);

    // layer 2: Ah -> Hh; agg (+resid Ah) -> Ch
    gemm_mfma_h<<<gemm_grid, 256, 0, stream>>>(Ah, Wsw2, Hh);
    agg_ln<<<agg_grid, 256, 0, stream>>>(Hh, Ah, dinv, b[2], g[2], be[2], rowptr, rec, Ch);

    classifier_mfma<<<gemm_grid, 256, 0, stream>>>(Ch, Wcsw, bc, out);
}

// Round 11
// 495.806 us; speedup vs baseline: 1.0326x; 1.0326x over previous
//
#include <hip/hip_runtime.h>
#include <math.h>

#define N_NODES 100000
#define N_EDGES 1600000
#define DIM     128
#define NCLS    40
#define SCAN_BLOCKS 98   // ceil(100000/1024)
#define NBUCK   196      // ceil(100000/512) buckets of 512 nodes
#define P1_CH   4096     // edges per phase-1 block
#define P1_GRID 391      // ceil(1600000/4096)

typedef _Float16 f16x8 __attribute__((ext_vector_type(8)));
typedef _Float16 f16x2 __attribute__((ext_vector_type(2)));
typedef float    f32x4 __attribute__((ext_vector_type(4)));

__device__ inline unsigned short f16bits(float f) {
    union { _Float16 h; unsigned short u; } cv;
    cv.h = (_Float16)f;
    return cv.u;
}
__device__ inline f16x2 as_h2(unsigned u) {
    union { unsigned u; f16x2 h; } cv;
    cv.u = u;
    return cv.h;
}
__device__ inline unsigned as_u(f16x2 h) {
    union { f16x2 h; unsigned u; } cv;
    cv.h = h;
    return cv.u;
}
__device__ inline unsigned pack_h2(float lo, float hi) {
    f16x2 h;
    h.x = (_Float16)lo;
    h.y = (_Float16)hi;
    return as_u(h);
}

// ---------------------------------------------------------------- degree (int)
__global__ __launch_bounds__(256) void deg_count(const int* __restrict__ ei,
                                                 int* __restrict__ degi) {
    int e = blockIdx.x * 256 + threadIdx.x;
    if (e < N_EDGES) atomicAdd(&degi[ei[N_EDGES + e]], 1);
}

__global__ __launch_bounds__(256) void finalize_dinv(const int* __restrict__ degi,
                                                     float* __restrict__ dinv) {
    int n = blockIdx.x * 256 + threadIdx.x;
    if (n < N_NODES) dinv[n] = rsqrtf((float)degi[n] + 1.0f);
}

// ---------------------------------------------------------------- scan (exclusive) over degi -> rowptr
__global__ __launch_bounds__(256) void scan1(const int* __restrict__ degi,
                                             int* __restrict__ rowptr,
                                             int* __restrict__ bsums) {
    __shared__ int sums[256];
    int t    = threadIdx.x;
    int base = blockIdx.x * 1024 + t * 4;
    int v[4], s = 0;
#pragma unroll
    for (int i = 0; i < 4; ++i) {
        int idx = base + i;
        v[i] = (idx < N_NODES) ? degi[idx] : 0;
        s += v[i];
    }
    sums[t] = s;
    __syncthreads();
    for (int off = 1; off < 256; off <<= 1) {
        int x = (t >= off) ? sums[t - off] : 0;
        __syncthreads();
        sums[t] += x;
        __syncthreads();
    }
    int run = (t == 0) ? 0 : sums[t - 1];
#pragma unroll
    for (int i = 0; i < 4; ++i) {
        int idx = base + i;
        if (idx < N_NODES) rowptr[idx] = run;
        run += v[i];
    }
    if (t == 255) bsums[blockIdx.x] = sums[255];
}

__global__ __launch_bounds__(128) void scan2(int* __restrict__ bsums) {
    __shared__ int s[128];
    int t = threadIdx.x;
    s[t] = (t < SCAN_BLOCKS) ? bsums[t] : 0;
    __syncthreads();
    for (int off = 1; off < 128; off <<= 1) {
        int x = (t >= off) ? s[t - off] : 0;
        __syncthreads();
        s[t] += x;
        __syncthreads();
    }
    if (t < SCAN_BLOCKS) bsums[t] = (t == 0) ? 0 : s[t - 1];
}

__global__ __launch_bounds__(256) void scan3(int* __restrict__ rowptr,
                                             int* __restrict__ bcur,
                                             const int* __restrict__ bsums) {
    int idx = blockIdx.x * 256 + threadIdx.x;
    if (idx < N_NODES) {
        int v = rowptr[idx] + bsums[idx >> 10];
        rowptr[idx] = v;
        if ((idx & 511) == 0) bcur[idx >> 9] = v;   // bucket base cursor
    }
    if (idx == 0) rowptr[N_NODES] = N_EDGES;
}

// ---------------------------------------------------------------- phase 1: bucket edges by dst>>9 into tmp (coalesced runs)
__global__ __launch_bounds__(256) void bucket_p1(const int* __restrict__ ei,
                                                 int* __restrict__ bcur,
                                                 int2* __restrict__ tmp) {
    __shared__ int  hist[256];
    __shared__ int  lscan[256];
    __shared__ int  rank[256];
    __shared__ int  gbase[256];
    __shared__ int2 stage[P1_CH];      // 32 KB
    const int t  = threadIdx.x;
    const int e0 = blockIdx.x * P1_CH;
    const int cnt = min(P1_CH, N_EDGES - e0);

    hist[t] = 0;
    __syncthreads();

    int2 ed[16];
#pragma unroll
    for (int i = 0; i < 16; ++i) {
        int idx = t + i * 256;
        if (idx < cnt) {
            int s = ei[e0 + idx];
            int d = ei[N_EDGES + e0 + idx];
            ed[i] = make_int2(s, d);
            atomicAdd(&hist[d >> 9], 1);
        }
    }
    __syncthreads();

    int hv = hist[t];
    lscan[t] = hv;
    __syncthreads();
    for (int off = 1; off < 256; off <<= 1) {
        int x = (t >= off) ? lscan[t - off] : 0;
        __syncthreads();
        lscan[t] += x;
        __syncthreads();
    }
    int excl = (t == 0) ? 0 : lscan[t - 1];
    __syncthreads();
    lscan[t] = excl;
    rank[t]  = excl;
    if (hv > 0) gbase[t] = atomicAdd(&bcur[t], hv);
    __syncthreads();

#pragma unroll
    for (int i = 0; i < 16; ++i) {
        int idx = t + i * 256;
        if (idx < cnt) {
            int b = ed[i].y >> 9;
            int p = atomicAdd(&rank[b], 1);
            stage[p] = ed[i];
        }
    }
    __syncthreads();

    for (int p = t; p < cnt; p += 256) {
        int2 v = stage[p];
        int b = v.y >> 9;
        tmp[gbase[b] + (p - lscan[b])] = v;
    }
}

// ---------------------------------------------------------------- phase 2: within-bucket scatter; rec = (src*256, half2(w,w))
__global__ __launch_bounds__(256) void bucket_p2(const int2* __restrict__ tmp,
                                                 const int* __restrict__ rowptr,
                                                 const float* __restrict__ dinv,
                                                 int2* __restrict__ rec) {
    __shared__ int cur[512];
    const int t  = threadIdx.x;
    const int b  = blockIdx.x;
    const int d0 = b << 9;
    const int dend = min(d0 + 512, N_NODES);
    const int nn = dend - d0;

    for (int i = t; i < nn; i += 256) cur[i] = rowptr[d0 + i];
    __syncthreads();

    const int beg = rowptr[d0];
    const int end = rowptr[dend];
    for (int idx = beg + t; idx < end; idx += 256) {
        int2 v = tmp[idx];
        int s = v.x, d = v.y;
        int pos = atomicAdd(&cur[d - d0], 1);
        unsigned short wb = f16bits(dinv[s] * dinv[d]);
        rec[pos] = make_int2(s << 8, (int)((unsigned)wb | ((unsigned)wb << 16)));
    }
}

// ---------------------------------------------------------------- W pre-swizzle into MFMA B-fragment order (f16)
__global__ __launch_bounds__(256) void wswz(const float* __restrict__ W,
                                            unsigned short* __restrict__ Wsw) {
    int o = blockIdx.x * 256 + threadIdx.x;      // 0..16383
    int f = o >> 9;
    int l = (o >> 3) & 63;
    int j = o & 7;
    int n = f >> 2;
    int s = f & 3;
    int k = s * 32 + (l >> 4) * 8 + j;
    int c = (l & 15) * 8 + n;
    Wsw[o] = f16bits(W[k * DIM + c]);
}

// ---------------------------------------------------------------- Wc pre-swizzle (128x40 -> 3 n-tiles, c = 3m+n), f16
__global__ __launch_bounds__(256) void wcswz(const float* __restrict__ Wc,
                                             unsigned short* __restrict__ Wcsw) {
    int o = blockIdx.x * 256 + threadIdx.x;      // 0..6143
    if (o >= 12 * 512) return;
    int f = o >> 9;
    int l = (o >> 3) & 63;
    int j = o & 7;
    int n = f >> 2;
    int s = f & 3;
    int k = s * 32 + (l >> 4) * 8 + j;
    int c = (l & 15) * 3 + n;
    Wcsw[o] = (c < NCLS) ? f16bits(Wc[k * NCLS + c]) : (unsigned short)0;
}

// ---------------------------------------------------------------- MFMA GEMM, fp32 input (layer 0): H(f16) = X @ W
__global__ __launch_bounds__(256, 2) void gemm_mfma_f(const float* __restrict__ X,
                                                      const unsigned short* __restrict__ Wsw,
                                                      unsigned short* __restrict__ H) {
    const int lane  = threadIdx.x & 63;
    const int wave  = threadIdx.x >> 6;
    const int row0w = blockIdx.x * 64 + wave * 16;
    const int m = lane & 15;
    const int q = lane >> 4;

    f16x8 wf[32];
#pragma unroll
    for (int f = 0; f < 32; ++f)
        wf[f] = *(const f16x8*)(Wsw + (f << 9) + lane * 8);

    int r = row0w + m;
    if (r >= N_NODES) r = N_NODES - 1;
    const float* xp = X + (size_t)r * DIM + q * 8;
    f16x8 af[4];
#pragma unroll
    for (int s = 0; s < 4; ++s) {
        float4 x0 = *(const float4*)(xp + s * 32);
        float4 x1 = *(const float4*)(xp + s * 32 + 4);
        f16x8 v;
        v[0] = (_Float16)x0.x; v[1] = (_Float16)x0.y;
        v[2] = (_Float16)x0.z; v[3] = (_Float16)x0.w;
        v[4] = (_Float16)x1.x; v[5] = (_Float16)x1.y;
        v[6] = (_Float16)x1.z; v[7] = (_Float16)x1.w;
        af[s] = v;
    }

    f32x4 acc[8];
    f32x4 z = {0.f, 0.f, 0.f, 0.f};
#pragma unroll
    for (int n = 0; n < 8; ++n) acc[n] = z;

#pragma unroll
    for (int s = 0; s < 4; ++s)
#pragma unroll
        for (int n = 0; n < 8; ++n)
            acc[n] = __builtin_amdgcn_mfma_f32_16x16x32_f16(af[s], wf[n * 4 + s], acc[n], 0, 0, 0);

#pragma unroll
    for (int j = 0; j < 4; ++j) {
        int row = row0w + q * 4 + j;
        if (row < N_NODES) {
            uint4 o;
            o.x = pack_h2(acc[0][j], acc[1][j]);
            o.y = pack_h2(acc[2][j], acc[3][j]);
            o.z = pack_h2(acc[4][j], acc[5][j]);
            o.w = pack_h2(acc[6][j], acc[7][j]);
            *(uint4*)(H + (size_t)row * DIM + m * 8) = o;
        }
    }
}

// ---------------------------------------------------------------- MFMA GEMM, f16 input (layers 1,2)
__global__ __launch_bounds__(256, 2) void gemm_mfma_h(const unsigned short* __restrict__ Xh,
                                                      const unsigned short* __restrict__ Wsw,
                                                      unsigned short* __restrict__ H) {
    const int lane  = threadIdx.x & 63;
    const int wave  = threadIdx.x >> 6;
    const int row0w = blockIdx.x * 64 + wave * 16;
    const int m = lane & 15;
    const int q = lane >> 4;

    f16x8 wf[32];
#pragma unroll
    for (int f = 0; f < 32; ++f)
        wf[f] = *(const f16x8*)(Wsw + (f << 9) + lane * 8);

    int r = row0w + m;
    if (r >= N_NODES) r = N_NODES - 1;
    const unsigned short* xp = Xh + (size_t)r * DIM + q * 8;
    f16x8 af[4];
#pragma unroll
    for (int s = 0; s < 4; ++s) af[s] = *(const f16x8*)(xp + s * 32);

    f32x4 acc[8];
    f32x4 z = {0.f, 0.f, 0.f, 0.f};
#pragma unroll
    for (int n = 0; n < 8; ++n) acc[n] = z;

#pragma unroll
    for (int s = 0; s < 4; ++s)
#pragma unroll
        for (int n = 0; n < 8; ++n)
            acc[n] = __builtin_amdgcn_mfma_f32_16x16x32_f16(af[s], wf[n * 4 + s], acc[n], 0, 0, 0);

#pragma unroll
    for (int j = 0; j < 4; ++j) {
        int row = row0w + q * 4 + j;
        if (row < N_NODES) {
            uint4 o;
            o.x = pack_h2(acc[0][j], acc[1][j]);
            o.y = pack_h2(acc[2][j], acc[3][j]);
            o.z = pack_h2(acc[4][j], acc[5][j]);
            o.w = pack_h2(acc[6][j], acc[7][j]);
            *(uint4*)(H + (size_t)row * DIM + m * 8) = o;
        }
    }
}

// ---------------------------------------------------------------- fused gather-aggregate + LN + ELU (+ residual), f16
// One wave per node. Gather: quarter-split (qtr=lane>>4 handles every 4th
// edge; lane loads 16B = cols sub*8..+7), pk_fma f16 accumulate, rec.x holds
// src*256 (byte offset). Epilogue: quarter-merge, then each lane owns 2 cols
// (c0 = sub*8+qtr*2) -> 2 expm1/lane, 64-lane LN reduction, 4B store/lane.
__global__ __launch_bounds__(256) void agg_ln(const unsigned short* __restrict__ Hh,
                                              const unsigned short* __restrict__ xin,
                                              const float* __restrict__ dinv,
                                              const float* __restrict__ bias,
                                              const float* __restrict__ g,
                                              const float* __restrict__ be,
                                              const int* __restrict__ rowptr,
                                              const int2* __restrict__ rec,
                                              unsigned short* __restrict__ outb) {
    int node = blockIdx.x * 4 + (threadIdx.x >> 6);
    int lane = threadIdx.x & 63;
    int sub  = lane & 15;
    int qtr  = lane >> 4;
    int beg = rowptr[node];
    int end = rowptr[node + 1];
    const char* Hb8 = (const char*)Hh;
    const unsigned laneoff = (unsigned)sub * 16;   // byte offset within row

    f16x2 acc[4];
    f16x2 hz = {(_Float16)0.f, (_Float16)0.f};
#pragma unroll
    for (int k = 0; k < 4; ++k) acc[k] = hz;

    for (int e0 = beg; e0 < end; e0 += 64) {
        int cnt = min(end - e0, 64);
        int2 rc = (lane < cnt) ? rec[e0 + lane] : make_int2(0, 0);
        int sv = rc.x;                        // src*256 byte offset (w=0 pads are harmless)
        int wv = rc.y;                        // packed half2 (w,w)
        int cntR = (cnt + 7) & ~7;
        for (int j = 0; j < cntR; j += 8) {
            int i0 = j + qtr, i1 = j + 4 + qtr;
            unsigned o0 = (unsigned)__shfl(sv, i0, 64) + laneoff;
            int      w0 = __shfl(wv, i0, 64);
            unsigned o1 = (unsigned)__shfl(sv, i1, 64) + laneoff;
            int      w1 = __shfl(wv, i1, 64);
            uint4 u0 = *(const uint4*)(Hb8 + o0);
            uint4 u1 = *(const uint4*)(Hb8 + o1);
            f16x2 hw0 = as_h2(w0), hw1 = as_h2(w1);
            acc[0] += as_h2(u0.x) * hw0;
            acc[1] += as_h2(u0.y) * hw0;
            acc[2] += as_h2(u0.z) * hw0;
            acc[3] += as_h2(u0.w) * hw0;
            acc[0] += as_h2(u1.x) * hw1;
            acc[1] += as_h2(u1.y) * hw1;
            acc[2] += as_h2(u1.z) * hw1;
            acc[3] += as_h2(u1.w) * hw1;
        }
    }

    // merge quarters (all lanes end with full col sums for cols sub*8..+7)
#pragma unroll
    for (int k = 0; k < 4; ++k) {
        acc[k] += as_h2(__shfl_xor(as_u(acc[k]), 16, 64));
        acc[k] += as_h2(__shfl_xor(as_u(acc[k]), 32, 64));
    }

    // each lane now owns cols c0 = sub*8 + qtr*2, c0+1  (pair = acc[qtr])
    unsigned mu = as_u(acc[0]);
    mu = (qtr == 1) ? as_u(acc[1]) : mu;
    mu = (qtr == 2) ? as_u(acc[2]) : mu;
    mu = (qtr == 3) ? as_u(acc[3]) : mu;
    f16x2 mine = as_h2(mu);
    const int c0 = sub * 8 + qtr * 2;
    const unsigned nodeoff = ((unsigned)node << 8) + (unsigned)c0 * 2;

    float dv = dinv[node];
    float d2 = dv * dv;
    f16x2 hh = as_h2(*(const unsigned*)(Hb8 + nodeoff));
    float2 bb = *(const float2*)(bias + c0);
    float a0 = (float)mine.x + (float)hh.x * d2 + bb.x;
    float a1 = (float)mine.y + (float)hh.y * d2 + bb.y;

    // LN stats across all 64 lanes (each col counted exactly once)
    float s1 = a0 + a1;
    float s2 = a0 * a0 + a1 * a1;
#pragma unroll
    for (int mk = 1; mk <= 32; mk <<= 1) {
        s1 += __shfl_xor(s1, mk, 64);
        s2 += __shfl_xor(s2, mk, 64);
    }
    float mean = s1 * (1.0f / 128.0f);
    float var  = s2 * (1.0f / 128.0f) - mean * mean;
    float rr   = rsqrtf(var + 1e-5f);
    float2 gg = *(const float2*)(g + c0);
    float2 ee = *(const float2*)(be + c0);
    float r0 = (a0 - mean) * rr * gg.x + ee.x;
    float r1 = (a1 - mean) * rr * gg.y + ee.y;
    r0 = r0 > 0.0f ? r0 : expm1f(r0);
    r1 = r1 > 0.0f ? r1 : expm1f(r1);
    if (xin) {
        f16x2 xi = as_h2(*(const unsigned*)((const char*)xin + nodeoff));
        r0 += (float)xi.x;
        r1 += (float)xi.y;
    }
    *(unsigned*)((char*)outb + nodeoff) = pack_h2(r0, r1);
}

// ---------------------------------------------------------------- MFMA classifier, f16 input: out = X @ Wc + bc
__global__ __launch_bounds__(256) void classifier_mfma(const unsigned short* __restrict__ Xh,
                                                       const unsigned short* __restrict__ Wcsw,
                                                       const float* __restrict__ bc,
                                                       float* __restrict__ out) {
    const int lane  = threadIdx.x & 63;
    const int wave  = threadIdx.x >> 6;
    const int row0w = blockIdx.x * 64 + wave * 16;
    const int m = lane & 15;
    const int q = lane >> 4;

    f16x8 wf[12];
#pragma unroll
    for (int f = 0; f < 12; ++f)
        wf[f] = *(const f16x8*)(Wcsw + (f << 9) + lane * 8);

    int r = row0w + m;
    if (r >= N_NODES) r = N_NODES - 1;
    const unsigned short* xp = Xh + (size_t)r * DIM + q * 8;
    f16x8 af[4];
#pragma unroll
    for (int s = 0; s < 4; ++s) af[s] = *(const f16x8*)(xp + s * 32);

    f32x4 acc[3];
    f32x4 z = {0.f, 0.f, 0.f, 0.f};
#pragma unroll
    for (int n = 0; n < 3; ++n) acc[n] = z;

#pragma unroll
    for (int s = 0; s < 4; ++s)
#pragma unroll
        for (int n = 0; n < 3; ++n)
            acc[n] = __builtin_amdgcn_mfma_f32_16x16x32_f16(af[s], wf[n * 4 + s], acc[n], 0, 0, 0);

    float bcv[3];
#pragma unroll
    for (int n = 0; n < 3; ++n) {
        int c = 3 * m + n;
        bcv[n] = (c < NCLS) ? bc[c] : 0.f;
    }

#pragma unroll
    for (int j = 0; j < 4; ++j) {
        int row = row0w + q * 4 + j;
        if (row < N_NODES) {
#pragma unroll
            for (int n = 0; n < 3; ++n) {
                int c = 3 * m + n;
                if (c < NCLS)
                    out[(size_t)row * NCLS + c] = acc[n][j] + bcv[n];
            }
        }
    }
}

// ---------------------------------------------------------------- launch
extern "C" void kernel_launch(void* const* d_in, const int* in_sizes, int n_in,
                              void* d_out, int out_size, void* d_ws, size_t ws_size,
                              hipStream_t stream) {
    const float* x  = (const float*)d_in[0];
    const int*   ei = (const int*)d_in[1];
    const float* W[3]  = {(const float*)d_in[2], (const float*)d_in[6], (const float*)d_in[10]};
    const float* b[3]  = {(const float*)d_in[3], (const float*)d_in[7], (const float*)d_in[11]};
    const float* g[3]  = {(const float*)d_in[4], (const float*)d_in[8], (const float*)d_in[12]};
    const float* be[3] = {(const float*)d_in[5], (const float*)d_in[9], (const float*)d_in[13]};
    const float* Wc = (const float*)d_in[14];
    const float* bc = (const float*)d_in[15];
    float* out = (float*)d_out;

    char* ws = (char*)d_ws;
    const size_t NP = 400128;  // padded N*4 bytes
    float* dinv   = (float*)(ws);
    int*   degi   = (int*)  (ws + NP);
    int*   rowptr = (int*)  (ws + 2 * NP);
    int*   bcur   = (int*)  (ws + 3 * NP);
    int*   bsums  = (int*)  (ws + 4 * NP);
    int2*  rec    = (int2*) (ws + 4 * NP + 512);
    unsigned short* Hh = (unsigned short*)(ws + 4 * NP + 512 + (size_t)N_EDGES * 8);
    unsigned short* Ah = Hh + (size_t)N_NODES * DIM;
    unsigned short* Ch = Ah + (size_t)N_NODES * DIM;
    unsigned short* Wsw0 = Ch + (size_t)N_NODES * DIM;
    unsigned short* Wsw1 = Wsw0 + DIM * DIM;
    unsigned short* Wsw2 = Wsw1 + DIM * DIM;
    unsigned short* Wcsw = Wsw2 + DIM * DIM;   // 12*512 shorts
    int2*  tmp    = (int2*)Ch;                 // aliases Ch; dead before layer 0 writes Ch

    // ---- W pre-swizzles (f16, MFMA B-frag order) ----
    wswz<<<64, 256, 0, stream>>>(W[0], Wsw0);
    wswz<<<64, 256, 0, stream>>>(W[1], Wsw1);
    wswz<<<64, 256, 0, stream>>>(W[2], Wsw2);
    wcswz<<<24, 256, 0, stream>>>(Wc, Wcsw);

    // ---- CSR build ----
    hipMemsetAsync(degi, 0, N_NODES * sizeof(int), stream);
    deg_count<<<(N_EDGES + 255) / 256, 256, 0, stream>>>(ei, degi);
    finalize_dinv<<<(N_NODES + 255) / 256, 256, 0, stream>>>(degi, dinv);
    scan1<<<SCAN_BLOCKS, 256, 0, stream>>>(degi, rowptr, bsums);
    scan2<<<1, 128, 0, stream>>>(bsums);
    scan3<<<SCAN_BLOCKS * 4, 256, 0, stream>>>(rowptr, bcur, bsums);
    bucket_p1<<<P1_GRID, 256, 0, stream>>>(ei, bcur, tmp);
    bucket_p2<<<NBUCK, 256, 0, stream>>>(tmp, rowptr, dinv, rec);

    const int gemm_grid = (N_NODES + 63) / 64;    // 1563
    const int agg_grid  = N_NODES / 4;            // 25000

    // layer 0: x fp32 -> Hh; agg -> Ch
    gemm_mfma_f<<<gemm_grid, 256, 0, stream>>>(x, Wsw0, Hh);
    agg_ln<<<agg_grid, 256, 0, stream>>>(Hh, nullptr, dinv, b[0], g[0], be[0], rowptr, rec, Ch);

    // layer 1: Ch -> Hh; agg (+resid Ch) -> Ah
    gemm_mfma_h<<<gemm_grid, 256, 0, stream>>>(Ch, Wsw1, Hh);
    agg_ln<<<agg_grid, 256, 0, stream>>>(Hh, Ch, dinv, b[1], g[1], be[1], rowptr, rec, Ah);

    // layer 2: Ah -> Hh; agg (+resid Ah) -> Ch
    gemm_mfma_h<<<gemm_grid, 256, 0, stream>>>(Ah, Wsw2, Hh);
    agg_ln<<<agg_grid, 256, 0, stream>>>(Hh, Ah, dinv, b[2], g[2], be[2], rowptr, rec, Ch);

    classifier_mfma<<<gemm_grid, 256, 0, stream>>>(Ch, Wcsw, bc, out);
}

// Round 12
// 480.843 us; speedup vs baseline: 1.0648x; 1.0311x over previous
//
#include <hip/hip_runtime.h>
#include <math.h>

#define N_NODES 100000
#define N_EDGES 1600000
#define DIM     128
#define NCLS    40
#define SCAN_BLOCKS 98   // ceil(100000/1024)
#define NBUCK   196      // ceil(100000/512) buckets of 512 nodes
#define P1_CH   4096     // edges per phase-1 block
#define P1_GRID 391      // ceil(1600000/4096)

typedef _Float16 f16x8 __attribute__((ext_vector_type(8)));
typedef _Float16 f16x2 __attribute__((ext_vector_type(2)));
typedef float    f32x4 __attribute__((ext_vector_type(4)));

__device__ inline unsigned short f16bits(float f) {
    union { _Float16 h; unsigned short u; } cv;
    cv.h = (_Float16)f;
    return cv.u;
}
__device__ inline f16x2 as_h2(unsigned u) {
    union { unsigned u; f16x2 h; } cv;
    cv.u = u;
    return cv.h;
}
__device__ inline unsigned as_u(f16x2 h) {
    union { f16x2 h; unsigned u; } cv;
    cv.h = h;
    return cv.u;
}
__device__ inline unsigned pack_h2(float lo, float hi) {
    f16x2 h;
    h.x = (_Float16)lo;
    h.y = (_Float16)hi;
    return as_u(h);
}

// ---------------------------------------------------------------- setup: all W swizzles (f16 MFMA B-frag order) + zero degi
// blocks 0..191: Wsw0/1/2 (64 each); 192..215: Wcsw; 216..255: zero degi
__global__ __launch_bounds__(256) void setup_misc(const float* __restrict__ W0,
                                                  const float* __restrict__ W1,
                                                  const float* __restrict__ W2,
                                                  const float* __restrict__ Wc,
                                                  unsigned short* __restrict__ Wsw0,
                                                  unsigned short* __restrict__ Wsw1,
                                                  unsigned short* __restrict__ Wsw2,
                                                  unsigned short* __restrict__ Wcsw,
                                                  int* __restrict__ degi) {
    int blk = blockIdx.x;
    if (blk < 192) {
        const float* W = (blk < 64) ? W0 : (blk < 128) ? W1 : W2;
        unsigned short* Wsw = (blk < 64) ? Wsw0 : (blk < 128) ? Wsw1 : Wsw2;
        int o = (blk & 63) * 256 + threadIdx.x;  // 0..16383
        int f = o >> 9;
        int l = (o >> 3) & 63;
        int j = o & 7;
        int n = f >> 2;
        int s = f & 3;
        int k = s * 32 + (l >> 4) * 8 + j;
        int c = (l & 15) * 8 + n;
        Wsw[o] = f16bits(W[k * DIM + c]);
    } else if (blk < 216) {
        int o = (blk - 192) * 256 + threadIdx.x; // 0..6143
        int f = o >> 9;
        int l = (o >> 3) & 63;
        int j = o & 7;
        int n = f >> 2;
        int s = f & 3;
        int k = s * 32 + (l >> 4) * 8 + j;
        int c = (l & 15) * 3 + n;
        Wcsw[o] = (c < NCLS) ? f16bits(Wc[k * NCLS + c]) : (unsigned short)0;
    } else {
        for (int i = (blk - 216) * 256 + threadIdx.x; i < N_NODES; i += 40 * 256)
            degi[i] = 0;
    }
}

// ---------------------------------------------------------------- degree (int)
__global__ __launch_bounds__(256) void deg_count(const int* __restrict__ ei,
                                                 int* __restrict__ degi) {
    int e = blockIdx.x * 256 + threadIdx.x;
    if (e < N_EDGES) atomicAdd(&degi[ei[N_EDGES + e]], 1);
}

// ---------------------------------------------------------------- scan (exclusive) over degi -> rowptr
__global__ __launch_bounds__(256) void scan1(const int* __restrict__ degi,
                                             int* __restrict__ rowptr,
                                             int* __restrict__ bsums) {
    __shared__ int sums[256];
    int t    = threadIdx.x;
    int base = blockIdx.x * 1024 + t * 4;
    int v[4], s = 0;
#pragma unroll
    for (int i = 0; i < 4; ++i) {
        int idx = base + i;
        v[i] = (idx < N_NODES) ? degi[idx] : 0;
        s += v[i];
    }
    sums[t] = s;
    __syncthreads();
    for (int off = 1; off < 256; off <<= 1) {
        int x = (t >= off) ? sums[t - off] : 0;
        __syncthreads();
        sums[t] += x;
        __syncthreads();
    }
    int run = (t == 0) ? 0 : sums[t - 1];
#pragma unroll
    for (int i = 0; i < 4; ++i) {
        int idx = base + i;
        if (idx < N_NODES) rowptr[idx] = run;
        run += v[i];
    }
    if (t == 255) bsums[blockIdx.x] = sums[255];
}

__global__ __launch_bounds__(128) void scan2(int* __restrict__ bsums) {
    __shared__ int s[128];
    int t = threadIdx.x;
    s[t] = (t < SCAN_BLOCKS) ? bsums[t] : 0;
    __syncthreads();
    for (int off = 1; off < 128; off <<= 1) {
        int x = (t >= off) ? s[t - off] : 0;
        __syncthreads();
        s[t] += x;
        __syncthreads();
    }
    if (t < SCAN_BLOCKS) bsums[t] = (t == 0) ? 0 : s[t - 1];
}

// scan3 + dinv fused
__global__ __launch_bounds__(256) void scan3(int* __restrict__ rowptr,
                                             int* __restrict__ bcur,
                                             const int* __restrict__ bsums,
                                             const int* __restrict__ degi,
                                             float* __restrict__ dinv) {
    int idx = blockIdx.x * 256 + threadIdx.x;
    if (idx < N_NODES) {
        int v = rowptr[idx] + bsums[idx >> 10];
        rowptr[idx] = v;
        if ((idx & 511) == 0) bcur[idx >> 9] = v;   // bucket base cursor
        dinv[idx] = rsqrtf((float)degi[idx] + 1.0f);
    }
    if (idx == 0) rowptr[N_NODES] = N_EDGES;
}

// ---------------------------------------------------------------- phase 1: bucket edges by dst>>9 into tmp (coalesced runs)
__global__ __launch_bounds__(256) void bucket_p1(const int* __restrict__ ei,
                                                 int* __restrict__ bcur,
                                                 int2* __restrict__ tmp) {
    __shared__ int  hist[256];
    __shared__ int  lscan[256];
    __shared__ int  rank[256];
    __shared__ int  gbase[256];
    __shared__ int2 stage[P1_CH];      // 32 KB
    const int t  = threadIdx.x;
    const int e0 = blockIdx.x * P1_CH;
    const int cnt = min(P1_CH, N_EDGES - e0);

    hist[t] = 0;
    __syncthreads();

    int2 ed[16];
#pragma unroll
    for (int i = 0; i < 16; ++i) {
        int idx = t + i * 256;
        if (idx < cnt) {
            int s = ei[e0 + idx];
            int d = ei[N_EDGES + e0 + idx];
            ed[i] = make_int2(s, d);
            atomicAdd(&hist[d >> 9], 1);
        }
    }
    __syncthreads();

    int hv = hist[t];
    lscan[t] = hv;
    __syncthreads();
    for (int off = 1; off < 256; off <<= 1) {
        int x = (t >= off) ? lscan[t - off] : 0;
        __syncthreads();
        lscan[t] += x;
        __syncthreads();
    }
    int excl = (t == 0) ? 0 : lscan[t - 1];
    __syncthreads();
    lscan[t] = excl;
    rank[t]  = excl;
    if (hv > 0) gbase[t] = atomicAdd(&bcur[t], hv);
    __syncthreads();

#pragma unroll
    for (int i = 0; i < 16; ++i) {
        int idx = t + i * 256;
        if (idx < cnt) {
            int b = ed[i].y >> 9;
            int p = atomicAdd(&rank[b], 1);
            stage[p] = ed[i];
        }
    }
    __syncthreads();

    for (int p = t; p < cnt; p += 256) {
        int2 v = stage[p];
        int b = v.y >> 9;
        tmp[gbase[b] + (p - lscan[b])] = v;
    }
}

// ---------------------------------------------------------------- phase 2: within-bucket scatter; rec = (src*256, half2(w,w))
__global__ __launch_bounds__(256) void bucket_p2(const int2* __restrict__ tmp,
                                                 const int* __restrict__ rowptr,
                                                 const float* __restrict__ dinv,
                                                 int2* __restrict__ rec) {
    __shared__ int cur[512];
    const int t  = threadIdx.x;
    const int b  = blockIdx.x;
    const int d0 = b << 9;
    const int dend = min(d0 + 512, N_NODES);
    const int nn = dend - d0;

    for (int i = t; i < nn; i += 256) cur[i] = rowptr[d0 + i];
    __syncthreads();

    const int beg = rowptr[d0];
    const int end = rowptr[dend];
    for (int idx = beg + t; idx < end; idx += 256) {
        int2 v = tmp[idx];
        int s = v.x, d = v.y;
        int pos = atomicAdd(&cur[d - d0], 1);
        unsigned short wb = f16bits(dinv[s] * dinv[d]);
        rec[pos] = make_int2(s << 8, (int)((unsigned)wb | ((unsigned)wb << 16)));
    }
}

// ---------------------------------------------------------------- MFMA GEMM, fp32 input (layer 0): 32 rows/wave, 128/block
__global__ __launch_bounds__(256, 2) void gemm_mfma_f(const float* __restrict__ X,
                                                      const unsigned short* __restrict__ Wsw,
                                                      unsigned short* __restrict__ H) {
    const int lane  = threadIdx.x & 63;
    const int wave  = threadIdx.x >> 6;
    const int row0w = blockIdx.x * 128 + wave * 32;
    const int m = lane & 15;
    const int q = lane >> 4;

    f16x8 wf[32];
#pragma unroll
    for (int f = 0; f < 32; ++f)
        wf[f] = *(const f16x8*)(Wsw + (f << 9) + lane * 8);

    f16x8 af[2][4];
#pragma unroll
    for (int ggr = 0; ggr < 2; ++ggr) {
        int r = row0w + ggr * 16 + m;
        if (r >= N_NODES) r = N_NODES - 1;
        const float* xp = X + (size_t)r * DIM + q * 8;
#pragma unroll
        for (int s = 0; s < 4; ++s) {
            float4 x0 = *(const float4*)(xp + s * 32);
            float4 x1 = *(const float4*)(xp + s * 32 + 4);
            f16x8 v;
            v[0] = (_Float16)x0.x; v[1] = (_Float16)x0.y;
            v[2] = (_Float16)x0.z; v[3] = (_Float16)x0.w;
            v[4] = (_Float16)x1.x; v[5] = (_Float16)x1.y;
            v[6] = (_Float16)x1.z; v[7] = (_Float16)x1.w;
            af[ggr][s] = v;
        }
    }

    f32x4 acc[2][8];
    f32x4 z = {0.f, 0.f, 0.f, 0.f};
#pragma unroll
    for (int ggr = 0; ggr < 2; ++ggr)
#pragma unroll
        for (int n = 0; n < 8; ++n) acc[ggr][n] = z;

#pragma unroll
    for (int s = 0; s < 4; ++s)
#pragma unroll
        for (int n = 0; n < 8; ++n) {
            acc[0][n] = __builtin_amdgcn_mfma_f32_16x16x32_f16(af[0][s], wf[n * 4 + s], acc[0][n], 0, 0, 0);
            acc[1][n] = __builtin_amdgcn_mfma_f32_16x16x32_f16(af[1][s], wf[n * 4 + s], acc[1][n], 0, 0, 0);
        }

#pragma unroll
    for (int ggr = 0; ggr < 2; ++ggr)
#pragma unroll
        for (int j = 0; j < 4; ++j) {
            int row = row0w + ggr * 16 + q * 4 + j;
            if (row < N_NODES) {
                uint4 o;
                o.x = pack_h2(acc[ggr][0][j], acc[ggr][1][j]);
                o.y = pack_h2(acc[ggr][2][j], acc[ggr][3][j]);
                o.z = pack_h2(acc[ggr][4][j], acc[ggr][5][j]);
                o.w = pack_h2(acc[ggr][6][j], acc[ggr][7][j]);
                *(uint4*)(H + (size_t)row * DIM + m * 8) = o;
            }
        }
}

// ---------------------------------------------------------------- MFMA GEMM, f16 input (layers 1,2): 32 rows/wave
__global__ __launch_bounds__(256, 2) void gemm_mfma_h(const unsigned short* __restrict__ Xh,
                                                      const unsigned short* __restrict__ Wsw,
                                                      unsigned short* __restrict__ H) {
    const int lane  = threadIdx.x & 63;
    const int wave  = threadIdx.x >> 6;
    const int row0w = blockIdx.x * 128 + wave * 32;
    const int m = lane & 15;
    const int q = lane >> 4;

    f16x8 wf[32];
#pragma unroll
    for (int f = 0; f < 32; ++f)
        wf[f] = *(const f16x8*)(Wsw + (f << 9) + lane * 8);

    f16x8 af[2][4];
#pragma unroll
    for (int ggr = 0; ggr < 2; ++ggr) {
        int r = row0w + ggr * 16 + m;
        if (r >= N_NODES) r = N_NODES - 1;
        const unsigned short* xp = Xh + (size_t)r * DIM + q * 8;
#pragma unroll
        for (int s = 0; s < 4; ++s) af[ggr][s] = *(const f16x8*)(xp + s * 32);
    }

    f32x4 acc[2][8];
    f32x4 z = {0.f, 0.f, 0.f, 0.f};
#pragma unroll
    for (int ggr = 0; ggr < 2; ++ggr)
#pragma unroll
        for (int n = 0; n < 8; ++n) acc[ggr][n] = z;

#pragma unroll
    for (int s = 0; s < 4; ++s)
#pragma unroll
        for (int n = 0; n < 8; ++n) {
            acc[0][n] = __builtin_amdgcn_mfma_f32_16x16x32_f16(af[0][s], wf[n * 4 + s], acc[0][n], 0, 0, 0);
            acc[1][n] = __builtin_amdgcn_mfma_f32_16x16x32_f16(af[1][s], wf[n * 4 + s], acc[1][n], 0, 0, 0);
        }

#pragma unroll
    for (int ggr = 0; ggr < 2; ++ggr)
#pragma unroll
        for (int j = 0; j < 4; ++j) {
            int row = row0w + ggr * 16 + q * 4 + j;
            if (row < N_NODES) {
                uint4 o;
                o.x = pack_h2(acc[ggr][0][j], acc[ggr][1][j]);
                o.y = pack_h2(acc[ggr][2][j], acc[ggr][3][j]);
                o.z = pack_h2(acc[ggr][4][j], acc[ggr][5][j]);
                o.w = pack_h2(acc[ggr][6][j], acc[ggr][7][j]);
                *(uint4*)(H + (size_t)row * DIM + m * 8) = o;
            }
        }
}

// ---------------------------------------------------------------- fused gather-aggregate + LN + ELU (+ residual), f16
__global__ __launch_bounds__(256) void agg_ln(const unsigned short* __restrict__ Hh,
                                              const unsigned short* __restrict__ xin,
                                              const float* __restrict__ dinv,
                                              const float* __restrict__ bias,
                                              const float* __restrict__ g,
                                              const float* __restrict__ be,
                                              const int* __restrict__ rowptr,
                                              const int2* __restrict__ rec,
                                              unsigned short* __restrict__ outb) {
    int node = blockIdx.x * 4 + (threadIdx.x >> 6);
    int lane = threadIdx.x & 63;
    int sub  = lane & 15;
    int qtr  = lane >> 4;
    int beg = rowptr[node];
    int end = rowptr[node + 1];
    const char* Hb8 = (const char*)Hh;
    const unsigned laneoff = (unsigned)sub * 16;   // byte offset within row

    f16x2 acc[4];
    f16x2 hz = {(_Float16)0.f, (_Float16)0.f};
#pragma unroll
    for (int k = 0; k < 4; ++k) acc[k] = hz;

    for (int e0 = beg; e0 < end; e0 += 64) {
        int cnt = min(end - e0, 64);
        int2 rc = (lane < cnt) ? rec[e0 + lane] : make_int2(0, 0);
        int sv = rc.x;                        // src*256 byte offset (w=0 pads harmless)
        int wv = rc.y;                        // packed half2 (w,w)
        int cntR = (cnt + 7) & ~7;
        for (int j = 0; j < cntR; j += 8) {
            int i0 = j + qtr, i1 = j + 4 + qtr;
            unsigned o0 = (unsigned)__shfl(sv, i0, 64) + laneoff;
            int      w0 = __shfl(wv, i0, 64);
            unsigned o1 = (unsigned)__shfl(sv, i1, 64) + laneoff;
            int      w1 = __shfl(wv, i1, 64);
            uint4 u0 = *(const uint4*)(Hb8 + o0);
            uint4 u1 = *(const uint4*)(Hb8 + o1);
            f16x2 hw0 = as_h2(w0), hw1 = as_h2(w1);
            acc[0] += as_h2(u0.x) * hw0;
            acc[1] += as_h2(u0.y) * hw0;
            acc[2] += as_h2(u0.z) * hw0;
            acc[3] += as_h2(u0.w) * hw0;
            acc[0] += as_h2(u1.x) * hw1;
            acc[1] += as_h2(u1.y) * hw1;
            acc[2] += as_h2(u1.z) * hw1;
            acc[3] += as_h2(u1.w) * hw1;
        }
    }

#pragma unroll
    for (int k = 0; k < 4; ++k) {
        acc[k] += as_h2(__shfl_xor(as_u(acc[k]), 16, 64));
        acc[k] += as_h2(__shfl_xor(as_u(acc[k]), 32, 64));
    }

    unsigned mu = as_u(acc[0]);
    mu = (qtr == 1) ? as_u(acc[1]) : mu;
    mu = (qtr == 2) ? as_u(acc[2]) : mu;
    mu = (qtr == 3) ? as_u(acc[3]) : mu;
    f16x2 mine = as_h2(mu);
    const int c0 = sub * 8 + qtr * 2;
    const unsigned nodeoff = ((unsigned)node << 8) + (unsigned)c0 * 2;

    float dv = dinv[node];
    float d2 = dv * dv;
    f16x2 hh = as_h2(*(const unsigned*)(Hb8 + nodeoff));
    float2 bb = *(const float2*)(bias + c0);
    float a0 = (float)mine.x + (float)hh.x * d2 + bb.x;
    float a1 = (float)mine.y + (float)hh.y * d2 + bb.y;

    float s1 = a0 + a1;
    float s2 = a0 * a0 + a1 * a1;
#pragma unroll
    for (int mk = 1; mk <= 32; mk <<= 1) {
        s1 += __shfl_xor(s1, mk, 64);
        s2 += __shfl_xor(s2, mk, 64);
    }
    float mean = s1 * (1.0f / 128.0f);
    float var  = s2 * (1.0f / 128.0f) - mean * mean;
    float rr   = rsqrtf(var + 1e-5f);
    float2 gg = *(const float2*)(g + c0);
    float2 ee = *(const float2*)(be + c0);
    float r0 = (a0 - mean) * rr * gg.x + ee.x;
    float r1 = (a1 - mean) * rr * gg.y + ee.y;
    r0 = r0 > 0.0f ? r0 : expm1f(r0);
    r1 = r1 > 0.0f ? r1 : expm1f(r1);
    if (xin) {
        f16x2 xi = as_h2(*(const unsigned*)((const char*)xin + nodeoff));
        r0 += (float)xi.x;
        r1 += (float)xi.y;
    }
    *(unsigned*)((char*)outb + nodeoff) = pack_h2(r0, r1);
}

// ---------------------------------------------------------------- MFMA classifier, f16 input: 32 rows/wave
__global__ __launch_bounds__(256) void classifier_mfma(const unsigned short* __restrict__ Xh,
                                                       const unsigned short* __restrict__ Wcsw,
                                                       const float* __restrict__ bc,
                                                       float* __restrict__ out) {
    const int lane  = threadIdx.x & 63;
    const int wave  = threadIdx.x >> 6;
    const int row0w = blockIdx.x * 128 + wave * 32;
    const int m = lane & 15;
    const int q = lane >> 4;

    f16x8 wf[12];
#pragma unroll
    for (int f = 0; f < 12; ++f)
        wf[f] = *(const f16x8*)(Wcsw + (f << 9) + lane * 8);

    f16x8 af[2][4];
#pragma unroll
    for (int ggr = 0; ggr < 2; ++ggr) {
        int r = row0w + ggr * 16 + m;
        if (r >= N_NODES) r = N_NODES - 1;
        const unsigned short* xp = Xh + (size_t)r * DIM + q * 8;
#pragma unroll
        for (int s = 0; s < 4; ++s) af[ggr][s] = *(const f16x8*)(xp + s * 32);
    }

    f32x4 acc[2][3];
    f32x4 z = {0.f, 0.f, 0.f, 0.f};
#pragma unroll
    for (int ggr = 0; ggr < 2; ++ggr)
#pragma unroll
        for (int n = 0; n < 3; ++n) acc[ggr][n] = z;

#pragma unroll
    for (int s = 0; s < 4; ++s)
#pragma unroll
        for (int n = 0; n < 3; ++n) {
            acc[0][n] = __builtin_amdgcn_mfma_f32_16x16x32_f16(af[0][s], wf[n * 4 + s], acc[0][n], 0, 0, 0);
            acc[1][n] = __builtin_amdgcn_mfma_f32_16x16x32_f16(af[1][s], wf[n * 4 + s], acc[1][n], 0, 0, 0);
        }

    float bcv[3];
#pragma unroll
    for (int n = 0; n < 3; ++n) {
        int c = 3 * m + n;
        bcv[n] = (c < NCLS) ? bc[c] : 0.f;
    }

#pragma unroll
    for (int ggr = 0; ggr < 2; ++ggr)
#pragma unroll
        for (int j = 0; j < 4; ++j) {
            int row = row0w + ggr * 16 + q * 4 + j;
            if (row < N_NODES) {
#pragma unroll
                for (int n = 0; n < 3; ++n) {
                    int c = 3 * m + n;
                    if (c < NCLS)
                        out[(size_t)row * NCLS + c] = acc[ggr][n][j] + bcv[n];
                }
            }
        }
}

// ---------------------------------------------------------------- launch
extern "C" void kernel_launch(void* const* d_in, const int* in_sizes, int n_in,
                              void* d_out, int out_size, void* d_ws, size_t ws_size,
                              hipStream_t stream) {
    const float* x  = (const float*)d_in[0];
    const int*   ei = (const int*)d_in[1];
    const float* W[3]  = {(const float*)d_in[2], (const float*)d_in[6], (const float*)d_in[10]};
    const float* b[3]  = {(const float*)d_in[3], (const float*)d_in[7], (const float*)d_in[11]};
    const float* g[3]  = {(const float*)d_in[4], (const float*)d_in[8], (const float*)d_in[12]};
    const float* be[3] = {(const float*)d_in[5], (const float*)d_in[9], (const float*)d_in[13]};
    const float* Wc = (const float*)d_in[14];
    const float* bc = (const float*)d_in[15];
    float* out = (float*)d_out;

    char* ws = (char*)d_ws;
    const size_t NP = 400128;  // padded N*4 bytes
    float* dinv   = (float*)(ws);
    int*   degi   = (int*)  (ws + NP);
    int*   rowptr = (int*)  (ws + 2 * NP);
    int*   bcur   = (int*)  (ws + 3 * NP);
    int*   bsums  = (int*)  (ws + 4 * NP);
    int2*  rec    = (int2*) (ws + 4 * NP + 512);
    unsigned short* Hh = (unsigned short*)(ws + 4 * NP + 512 + (size_t)N_EDGES * 8);
    unsigned short* Ah = Hh + (size_t)N_NODES * DIM;
    unsigned short* Ch = Ah + (size_t)N_NODES * DIM;
    unsigned short* Wsw0 = Ch + (size_t)N_NODES * DIM;
    unsigned short* Wsw1 = Wsw0 + DIM * DIM;
    unsigned short* Wsw2 = Wsw1 + DIM * DIM;
    unsigned short* Wcsw = Wsw2 + DIM * DIM;   // 12*512 shorts
    int2*  tmp    = (int2*)Ch;                 // aliases Ch; dead before layer 0 writes Ch

    // ---- setup: swizzles + zero degi (1 dispatch) ----
    setup_misc<<<256, 256, 0, stream>>>(W[0], W[1], W[2], Wc, Wsw0, Wsw1, Wsw2, Wcsw, degi);

    // ---- CSR build ----
    deg_count<<<(N_EDGES + 255) / 256, 256, 0, stream>>>(ei, degi);
    scan1<<<SCAN_BLOCKS, 256, 0, stream>>>(degi, rowptr, bsums);
    scan2<<<1, 128, 0, stream>>>(bsums);
    scan3<<<SCAN_BLOCKS * 4, 256, 0, stream>>>(rowptr, bcur, bsums, degi, dinv);
    bucket_p1<<<P1_GRID, 256, 0, stream>>>(ei, bcur, tmp);
    bucket_p2<<<NBUCK, 256, 0, stream>>>(tmp, rowptr, dinv, rec);

    const int gemm_grid = (N_NODES + 127) / 128;  // 782
    const int agg_grid  = N_NODES / 4;            // 25000

    // layer 0: x fp32 -> Hh; agg -> Ch
    gemm_mfma_f<<<gemm_grid, 256, 0, stream>>>(x, Wsw0, Hh);
    agg_ln<<<agg_grid, 256, 0, stream>>>(Hh, nullptr, dinv, b[0], g[0], be[0], rowptr, rec, Ch);

    // layer 1: Ch -> Hh; agg (+resid Ch) -> Ah
    gemm_mfma_h<<<gemm_grid, 256, 0, stream>>>(Ch, Wsw1, Hh);
    agg_ln<<<agg_grid, 256, 0, stream>>>(Hh, Ch, dinv, b[1], g[1], be[1], rowptr, rec, Ah);

    // layer 2: Ah -> Hh; agg (+resid Ah) -> Ch
    gemm_mfma_h<<<gemm_grid, 256, 0, stream>>>(Ah, Wsw2, Hh);
    agg_ln<<<agg_grid, 256, 0, stream>>>(Hh, Ah, dinv, b[2], g[2], be[2], rowptr, rec, Ch);

    classifier_mfma<<<gemm_grid, 256, 0, stream>>>(Ch, Wcsw, bc, out);
}

// Round 13
// 440.371 us; speedup vs baseline: 1.1626x; 1.0919x over previous
//
#include <hip/hip_runtime.h>
#include <math.h>

#define N_NODES 100000
#define N_EDGES 1600000
#define DIM     128
#define NCLS    40
#define NBUCK   196      // ceil(100000/512) buckets of 512 nodes
#define P1_CH   4096     // edges per phase-1 block
#define P1_GRID 391      // ceil(1600000/4096)

typedef _Float16 f16x8 __attribute__((ext_vector_type(8)));
typedef _Float16 f16x2 __attribute__((ext_vector_type(2)));
typedef float    f32x4 __attribute__((ext_vector_type(4)));

__device__ inline unsigned short f16bits(float f) {
    union { _Float16 h; unsigned short u; } cv;
    cv.h = (_Float16)f;
    return cv.u;
}
__device__ inline f16x2 as_h2(unsigned u) {
    union { unsigned u; f16x2 h; } cv;
    cv.u = u;
    return cv.h;
}
__device__ inline unsigned as_u(f16x2 h) {
    union { f16x2 h; unsigned u; } cv;
    cv.h = h;
    return cv.u;
}
__device__ inline unsigned pack_h2(float lo, float hi) {
    f16x2 h;
    h.x = (_Float16)lo;
    h.y = (_Float16)hi;
    return as_u(h);
}

// ---------------------------------------------------------------- setup: W swizzles (f16 MFMA B-frag order) + zero bcnt
// blocks 0..191: Wsw0/1/2; 192..215: Wcsw; 216: zero bcnt
__global__ __launch_bounds__(256) void setup_misc(const float* __restrict__ W0,
                                                  const float* __restrict__ W1,
                                                  const float* __restrict__ W2,
                                                  const float* __restrict__ Wc,
                                                  unsigned short* __restrict__ Wsw0,
                                                  unsigned short* __restrict__ Wsw1,
                                                  unsigned short* __restrict__ Wsw2,
                                                  unsigned short* __restrict__ Wcsw,
                                                  int* __restrict__ bcnt) {
    int blk = blockIdx.x;
    if (blk < 192) {
        const float* W = (blk < 64) ? W0 : (blk < 128) ? W1 : W2;
        unsigned short* Wsw = (blk < 64) ? Wsw0 : (blk < 128) ? Wsw1 : Wsw2;
        int o = (blk & 63) * 256 + threadIdx.x;  // 0..16383
        int f = o >> 9;
        int l = (o >> 3) & 63;
        int j = o & 7;
        int n = f >> 2;
        int s = f & 3;
        int k = s * 32 + (l >> 4) * 8 + j;
        int c = (l & 15) * 8 + n;
        Wsw[o] = f16bits(W[k * DIM + c]);
    } else if (blk < 216) {
        int o = (blk - 192) * 256 + threadIdx.x; // 0..6143
        int f = o >> 9;
        int l = (o >> 3) & 63;
        int j = o & 7;
        int n = f >> 2;
        int s = f & 3;
        int k = s * 32 + (l >> 4) * 8 + j;
        int c = (l & 15) * 3 + n;
        Wcsw[o] = (c < NCLS) ? f16bits(Wc[k * NCLS + c]) : (unsigned short)0;
    } else {
        bcnt[threadIdx.x] = 0;
    }
}

// ---------------------------------------------------------------- bucket histogram (LDS) -> 196 global counters
__global__ __launch_bounds__(256) void bhist(const int* __restrict__ ei,
                                             int* __restrict__ bcnt) {
    __shared__ int h[256];
    const int t  = threadIdx.x;
    const int e0 = blockIdx.x * P1_CH;
    const int cnt = min(P1_CH, N_EDGES - e0);
    h[t] = 0;
    __syncthreads();
    for (int i = t; i < cnt; i += 256)
        atomicAdd(&h[ei[N_EDGES + e0 + i] >> 9], 1);
    __syncthreads();
    if (h[t]) atomicAdd(&bcnt[t], h[t]);
}

// ---------------------------------------------------------------- bucket scan (1 block): bbase (exclusive), bcur = bbase
__global__ __launch_bounds__(256) void bscan(const int* __restrict__ bcnt,
                                             int* __restrict__ bbase,
                                             int* __restrict__ bcur) {
    __shared__ int s[256];
    int t = threadIdx.x;
    s[t] = (t < NBUCK) ? bcnt[t] : 0;
    __syncthreads();
    for (int off = 1; off < 256; off <<= 1) {
        int x = (t >= off) ? s[t - off] : 0;
        __syncthreads();
        s[t] += x;
        __syncthreads();
    }
    int excl = (t == 0) ? 0 : s[t - 1];
    if (t < NBUCK) {
        bbase[t] = excl;
        bcur[t]  = excl;
    }
    if (t == 0) bbase[NBUCK] = N_EDGES;
}

// ---------------------------------------------------------------- phase 1: bucket edges by dst>>9 into tmp (coalesced runs)
__global__ __launch_bounds__(256) void bucket_p1(const int* __restrict__ ei,
                                                 int* __restrict__ bcur,
                                                 int2* __restrict__ tmp) {
    __shared__ int  hist[256];
    __shared__ int  lscan[256];
    __shared__ int  rank[256];
    __shared__ int  gbase[256];
    __shared__ int2 stage[P1_CH];      // 32 KB
    const int t  = threadIdx.x;
    const int e0 = blockIdx.x * P1_CH;
    const int cnt = min(P1_CH, N_EDGES - e0);

    hist[t] = 0;
    __syncthreads();

    int2 ed[16];
#pragma unroll
    for (int i = 0; i < 16; ++i) {
        int idx = t + i * 256;
        if (idx < cnt) {
            int s = ei[e0 + idx];
            int d = ei[N_EDGES + e0 + idx];
            ed[i] = make_int2(s, d);
            atomicAdd(&hist[d >> 9], 1);
        }
    }
    __syncthreads();

    int hv = hist[t];
    lscan[t] = hv;
    __syncthreads();
    for (int off = 1; off < 256; off <<= 1) {
        int x = (t >= off) ? lscan[t - off] : 0;
        __syncthreads();
        lscan[t] += x;
        __syncthreads();
    }
    int excl = (t == 0) ? 0 : lscan[t - 1];
    __syncthreads();
    lscan[t] = excl;
    rank[t]  = excl;
    if (hv > 0) gbase[t] = atomicAdd(&bcur[t], hv);
    __syncthreads();

#pragma unroll
    for (int i = 0; i < 16; ++i) {
        int idx = t + i * 256;
        if (idx < cnt) {
            int b = ed[i].y >> 9;
            int p = atomicAdd(&rank[b], 1);
            stage[p] = ed[i];
        }
    }
    __syncthreads();

    for (int p = t; p < cnt; p += 256) {
        int2 v = stage[p];
        int b = v.y >> 9;
        tmp[gbase[b] + (p - lscan[b])] = v;
    }
}

// ---------------------------------------------------------------- phase 2a: per-bucket node counts (LDS) -> rowptr + dinv
__global__ __launch_bounds__(256) void bucket_p2a(const int2* __restrict__ tmp,
                                                  const int* __restrict__ bbase,
                                                  int* __restrict__ rowptr,
                                                  float* __restrict__ dinv) {
    __shared__ int cnt[512];
    __shared__ int pscan[256];
    const int t  = threadIdx.x;
    const int b  = blockIdx.x;
    const int d0 = b << 9;
    const int dend = min(d0 + 512, N_NODES);
    const int nn = dend - d0;

    cnt[t] = 0;
    cnt[t + 256] = 0;
    __syncthreads();

    const int beg = bbase[b];
    const int end = bbase[b + 1];
    for (int idx = beg + t; idx < end; idx += 256)
        atomicAdd(&cnt[tmp[idx].y - d0], 1);
    __syncthreads();

    int c0 = cnt[2 * t];
    int c1 = cnt[2 * t + 1];
    pscan[t] = c0 + c1;
    __syncthreads();
    for (int off = 1; off < 256; off <<= 1) {
        int x = (t >= off) ? pscan[t - off] : 0;
        __syncthreads();
        pscan[t] += x;
        __syncthreads();
    }
    int excl = (t == 0) ? 0 : pscan[t - 1];
    if (2 * t < nn) {
        rowptr[d0 + 2 * t] = beg + excl;
        dinv[d0 + 2 * t]   = rsqrtf((float)c0 + 1.0f);
    }
    if (2 * t + 1 < nn) {
        rowptr[d0 + 2 * t + 1] = beg + excl + c0;
        dinv[d0 + 2 * t + 1]   = rsqrtf((float)c1 + 1.0f);
    }
    if (b == NBUCK - 1 && t == 0) rowptr[N_NODES] = N_EDGES;
}

// ---------------------------------------------------------------- phase 2b: within-bucket scatter; rec = (src*256, half2(w,w))
__global__ __launch_bounds__(256) void bucket_p2b(const int2* __restrict__ tmp,
                                                  const int* __restrict__ rowptr,
                                                  const float* __restrict__ dinv,
                                                  int2* __restrict__ rec) {
    __shared__ int cur[512];
    const int t  = threadIdx.x;
    const int b  = blockIdx.x;
    const int d0 = b << 9;
    const int dend = min(d0 + 512, N_NODES);
    const int nn = dend - d0;

    for (int i = t; i < nn; i += 256) cur[i] = rowptr[d0 + i];
    __syncthreads();

    const int beg = rowptr[d0];
    const int end = rowptr[dend];
    for (int idx = beg + t; idx < end; idx += 256) {
        int2 v = tmp[idx];
        int s = v.x, d = v.y;
        int pos = atomicAdd(&cur[d - d0], 1);
        unsigned short wb = f16bits(dinv[s] * dinv[d]);
        rec[pos] = make_int2(s << 8, (int)((unsigned)wb | ((unsigned)wb << 16)));
    }
}

// ---------------------------------------------------------------- MFMA GEMM, fp32 input (layer 0): 32 rows/wave, 128/block
__global__ __launch_bounds__(256, 2) void gemm_mfma_f(const float* __restrict__ X,
                                                      const unsigned short* __restrict__ Wsw,
                                                      unsigned short* __restrict__ H) {
    const int lane  = threadIdx.x & 63;
    const int wave  = threadIdx.x >> 6;
    const int row0w = blockIdx.x * 128 + wave * 32;
    const int m = lane & 15;
    const int q = lane >> 4;

    f16x8 wf[32];
#pragma unroll
    for (int f = 0; f < 32; ++f)
        wf[f] = *(const f16x8*)(Wsw + (f << 9) + lane * 8);

    f16x8 af[2][4];
#pragma unroll
    for (int ggr = 0; ggr < 2; ++ggr) {
        int r = row0w + ggr * 16 + m;
        if (r >= N_NODES) r = N_NODES - 1;
        const float* xp = X + (size_t)r * DIM + q * 8;
#pragma unroll
        for (int s = 0; s < 4; ++s) {
            float4 x0 = *(const float4*)(xp + s * 32);
            float4 x1 = *(const float4*)(xp + s * 32 + 4);
            f16x8 v;
            v[0] = (_Float16)x0.x; v[1] = (_Float16)x0.y;
            v[2] = (_Float16)x0.z; v[3] = (_Float16)x0.w;
            v[4] = (_Float16)x1.x; v[5] = (_Float16)x1.y;
            v[6] = (_Float16)x1.z; v[7] = (_Float16)x1.w;
            af[ggr][s] = v;
        }
    }

    f32x4 acc[2][8];
    f32x4 z = {0.f, 0.f, 0.f, 0.f};
#pragma unroll
    for (int ggr = 0; ggr < 2; ++ggr)
#pragma unroll
        for (int n = 0; n < 8; ++n) acc[ggr][n] = z;

#pragma unroll
    for (int s = 0; s < 4; ++s)
#pragma unroll
        for (int n = 0; n < 8; ++n) {
            acc[0][n] = __builtin_amdgcn_mfma_f32_16x16x32_f16(af[0][s], wf[n * 4 + s], acc[0][n], 0, 0, 0);
            acc[1][n] = __builtin_amdgcn_mfma_f32_16x16x32_f16(af[1][s], wf[n * 4 + s], acc[1][n], 0, 0, 0);
        }

#pragma unroll
    for (int ggr = 0; ggr < 2; ++ggr)
#pragma unroll
        for (int j = 0; j < 4; ++j) {
            int row = row0w + ggr * 16 + q * 4 + j;
            if (row < N_NODES) {
                uint4 o;
                o.x = pack_h2(acc[ggr][0][j], acc[ggr][1][j]);
                o.y = pack_h2(acc[ggr][2][j], acc[ggr][3][j]);
                o.z = pack_h2(acc[ggr][4][j], acc[ggr][5][j]);
                o.w = pack_h2(acc[ggr][6][j], acc[ggr][7][j]);
                *(uint4*)(H + (size_t)row * DIM + m * 8) = o;
            }
        }
}

// ---------------------------------------------------------------- MFMA GEMM, f16 input (layers 1,2): 32 rows/wave
__global__ __launch_bounds__(256, 2) void gemm_mfma_h(const unsigned short* __restrict__ Xh,
                                                      const unsigned short* __restrict__ Wsw,
                                                      unsigned short* __restrict__ H) {
    const int lane  = threadIdx.x & 63;
    const int wave  = threadIdx.x >> 6;
    const int row0w = blockIdx.x * 128 + wave * 32;
    const int m = lane & 15;
    const int q = lane >> 4;

    f16x8 wf[32];
#pragma unroll
    for (int f = 0; f < 32; ++f)
        wf[f] = *(const f16x8*)(Wsw + (f << 9) + lane * 8);

    f16x8 af[2][4];
#pragma unroll
    for (int ggr = 0; ggr < 2; ++ggr) {
        int r = row0w + ggr * 16 + m;
        if (r >= N_NODES) r = N_NODES - 1;
        const unsigned short* xp = Xh + (size_t)r * DIM + q * 8;
#pragma unroll
        for (int s = 0; s < 4; ++s) af[ggr][s] = *(const f16x8*)(xp + s * 32);
    }

    f32x4 acc[2][8];
    f32x4 z = {0.f, 0.f, 0.f, 0.f};
#pragma unroll
    for (int ggr = 0; ggr < 2; ++ggr)
#pragma unroll
        for (int n = 0; n < 8; ++n) acc[ggr][n] = z;

#pragma unroll
    for (int s = 0; s < 4; ++s)
#pragma unroll
        for (int n = 0; n < 8; ++n) {
            acc[0][n] = __builtin_amdgcn_mfma_f32_16x16x32_f16(af[0][s], wf[n * 4 + s], acc[0][n], 0, 0, 0);
            acc[1][n] = __builtin_amdgcn_mfma_f32_16x16x32_f16(af[1][s], wf[n * 4 + s], acc[1][n], 0, 0, 0);
        }

#pragma unroll
    for (int ggr = 0; ggr < 2; ++ggr)
#pragma unroll
        for (int j = 0; j < 4; ++j) {
            int row = row0w + ggr * 16 + q * 4 + j;
            if (row < N_NODES) {
                uint4 o;
                o.x = pack_h2(acc[ggr][0][j], acc[ggr][1][j]);
                o.y = pack_h2(acc[ggr][2][j], acc[ggr][3][j]);
                o.z = pack_h2(acc[ggr][4][j], acc[ggr][5][j]);
                o.w = pack_h2(acc[ggr][6][j], acc[ggr][7][j]);
                *(uint4*)(H + (size_t)row * DIM + m * 8) = o;
            }
        }
}

// ---------------------------------------------------------------- fused gather-aggregate + LN + ELU (+ residual), f16
// Quarter-split gather, 4 loads in flight (j step 16), pk_fma accumulate.
__global__ __launch_bounds__(256) void agg_ln(const unsigned short* __restrict__ Hh,
                                              const unsigned short* __restrict__ xin,
                                              const float* __restrict__ dinv,
                                              const float* __restrict__ bias,
                                              const float* __restrict__ g,
                                              const float* __restrict__ be,
                                              const int* __restrict__ rowptr,
                                              const int2* __restrict__ rec,
                                              unsigned short* __restrict__ outb) {
    int node = blockIdx.x * 4 + (threadIdx.x >> 6);
    int lane = threadIdx.x & 63;
    int sub  = lane & 15;
    int qtr  = lane >> 4;
    int beg = rowptr[node];
    int end = rowptr[node + 1];
    const char* Hb8 = (const char*)Hh;
    const unsigned laneoff = (unsigned)sub * 16;   // byte offset within row

    f16x2 acc[4];
    f16x2 hz = {(_Float16)0.f, (_Float16)0.f};
#pragma unroll
    for (int k = 0; k < 4; ++k) acc[k] = hz;

    for (int e0 = beg; e0 < end; e0 += 64) {
        int cnt = min(end - e0, 64);
        int2 rc = (lane < cnt) ? rec[e0 + lane] : make_int2(0, 0);
        int sv = rc.x;                        // src*256 byte offset (pads have w=0)
        int wv = rc.y;                        // packed half2 (w,w)
        int cntR = (cnt + 15) & ~15;
        for (int j = 0; j < cntR; j += 16) {
            int i0 = j + qtr, i1 = j + 4 + qtr, i2 = j + 8 + qtr, i3 = j + 12 + qtr;
            unsigned o0 = (unsigned)__shfl(sv, i0, 64) + laneoff;
            int      w0 = __shfl(wv, i0, 64);
            unsigned o1 = (unsigned)__shfl(sv, i1, 64) + laneoff;
            int      w1 = __shfl(wv, i1, 64);
            unsigned o2 = (unsigned)__shfl(sv, i2, 64) + laneoff;
            int      w2 = __shfl(wv, i2, 64);
            unsigned o3 = (unsigned)__shfl(sv, i3, 64) + laneoff;
            int      w3 = __shfl(wv, i3, 64);
            uint4 u0 = *(const uint4*)(Hb8 + o0);
            uint4 u1 = *(const uint4*)(Hb8 + o1);
            uint4 u2 = *(const uint4*)(Hb8 + o2);
            uint4 u3 = *(const uint4*)(Hb8 + o3);
            f16x2 hw0 = as_h2(w0), hw1 = as_h2(w1), hw2 = as_h2(w2), hw3 = as_h2(w3);
            acc[0] += as_h2(u0.x) * hw0;
            acc[1] += as_h2(u0.y) * hw0;
            acc[2] += as_h2(u0.z) * hw0;
            acc[3] += as_h2(u0.w) * hw0;
            acc[0] += as_h2(u1.x) * hw1;
            acc[1] += as_h2(u1.y) * hw1;
            acc[2] += as_h2(u1.z) * hw1;
            acc[3] += as_h2(u1.w) * hw1;
            acc[0] += as_h2(u2.x) * hw2;
            acc[1] += as_h2(u2.y) * hw2;
            acc[2] += as_h2(u2.z) * hw2;
            acc[3] += as_h2(u2.w) * hw2;
            acc[0] += as_h2(u3.x) * hw3;
            acc[1] += as_h2(u3.y) * hw3;
            acc[2] += as_h2(u3.z) * hw3;
            acc[3] += as_h2(u3.w) * hw3;
        }
    }

#pragma unroll
    for (int k = 0; k < 4; ++k) {
        acc[k] += as_h2(__shfl_xor(as_u(acc[k]), 16, 64));
        acc[k] += as_h2(__shfl_xor(as_u(acc[k]), 32, 64));
    }

    unsigned mu = as_u(acc[0]);
    mu = (qtr == 1) ? as_u(acc[1]) : mu;
    mu = (qtr == 2) ? as_u(acc[2]) : mu;
    mu = (qtr == 3) ? as_u(acc[3]) : mu;
    f16x2 mine = as_h2(mu);
    const int c0 = sub * 8 + qtr * 2;
    const unsigned nodeoff = ((unsigned)node << 8) + (unsigned)c0 * 2;

    float dv = dinv[node];
    float d2 = dv * dv;
    f16x2 hh = as_h2(*(const unsigned*)(Hb8 + nodeoff));
    float2 bb = *(const float2*)(bias + c0);
    float a0 = (float)mine.x + (float)hh.x * d2 + bb.x;
    float a1 = (float)mine.y + (float)hh.y * d2 + bb.y;

    float s1 = a0 + a1;
    float s2 = a0 * a0 + a1 * a1;
#pragma unroll
    for (int mk = 1; mk <= 32; mk <<= 1) {
        s1 += __shfl_xor(s1, mk, 64);
        s2 += __shfl_xor(s2, mk, 64);
    }
    float mean = s1 * (1.0f / 128.0f);
    float var  = s2 * (1.0f / 128.0f) - mean * mean;
    float rr   = rsqrtf(var + 1e-5f);
    float2 gg = *(const float2*)(g + c0);
    float2 ee = *(const float2*)(be + c0);
    float r0 = (a0 - mean) * rr * gg.x + ee.x;
    float r1 = (a1 - mean) * rr * gg.y + ee.y;
    r0 = r0 > 0.0f ? r0 : expm1f(r0);
    r1 = r1 > 0.0f ? r1 : expm1f(r1);
    if (xin) {
        f16x2 xi = as_h2(*(const unsigned*)((const char*)xin + nodeoff));
        r0 += (float)xi.x;
        r1 += (float)xi.y;
    }
    *(unsigned*)((char*)outb + nodeoff) = pack_h2(r0, r1);
}

// ---------------------------------------------------------------- MFMA classifier, f16 input: 32 rows/wave
__global__ __launch_bounds__(256) void classifier_mfma(const unsigned short* __restrict__ Xh,
                                                       const unsigned short* __restrict__ Wcsw,
                                                       const float* __restrict__ bc,
                                                       float* __restrict__ out) {
    const int lane  = threadIdx.x & 63;
    const int wave  = threadIdx.x >> 6;
    const int row0w = blockIdx.x * 128 + wave * 32;
    const int m = lane & 15;
    const int q = lane >> 4;

    f16x8 wf[12];
#pragma unroll
    for (int f = 0; f < 12; ++f)
        wf[f] = *(const f16x8*)(Wcsw + (f << 9) + lane * 8);

    f16x8 af[2][4];
#pragma unroll
    for (int ggr = 0; ggr < 2; ++ggr) {
        int r = row0w + ggr * 16 + m;
        if (r >= N_NODES) r = N_NODES - 1;
        const unsigned short* xp = Xh + (size_t)r * DIM + q * 8;
#pragma unroll
        for (int s = 0; s < 4; ++s) af[ggr][s] = *(const f16x8*)(xp + s * 32);
    }

    f32x4 acc[2][3];
    f32x4 z = {0.f, 0.f, 0.f, 0.f};
#pragma unroll
    for (int ggr = 0; ggr < 2; ++ggr)
#pragma unroll
        for (int n = 0; n < 3; ++n) acc[ggr][n] = z;

#pragma unroll
    for (int s = 0; s < 4; ++s)
#pragma unroll
        for (int n = 0; n < 3; ++n) {
            acc[0][n] = __builtin_amdgcn_mfma_f32_16x16x32_f16(af[0][s], wf[n * 4 + s], acc[0][n], 0, 0, 0);
            acc[1][n] = __builtin_amdgcn_mfma_f32_16x16x32_f16(af[1][s], wf[n * 4 + s], acc[1][n], 0, 0, 0);
        }

    float bcv[3];
#pragma unroll
    for (int n = 0; n < 3; ++n) {
        int c = 3 * m + n;
        bcv[n] = (c < NCLS) ? bc[c] : 0.f;
    }

#pragma unroll
    for (int ggr = 0; ggr < 2; ++ggr)
#pragma unroll
        for (int j = 0; j < 4; ++j) {
            int row = row0w + ggr * 16 + q * 4 + j;
            if (row < N_NODES) {
#pragma unroll
                for (int n = 0; n < 3; ++n) {
                    int c = 3 * m + n;
                    if (c < NCLS)
                        out[(size_t)row * NCLS + c] = acc[ggr][n][j] + bcv[n];
                }
            }
        }
}

// ---------------------------------------------------------------- launch
extern "C" void kernel_launch(void* const* d_in, const int* in_sizes, int n_in,
                              void* d_out, int out_size, void* d_ws, size_t ws_size,
                              hipStream_t stream) {
    const float* x  = (const float*)d_in[0];
    const int*   ei = (const int*)d_in[1];
    const float* W[3]  = {(const float*)d_in[2], (const float*)d_in[6], (const float*)d_in[10]};
    const float* b[3]  = {(const float*)d_in[3], (const float*)d_in[7], (const float*)d_in[11]};
    const float* g[3]  = {(const float*)d_in[4], (const float*)d_in[8], (const float*)d_in[12]};
    const float* be[3] = {(const float*)d_in[5], (const float*)d_in[9], (const float*)d_in[13]};
    const float* Wc = (const float*)d_in[14];
    const float* bc = (const float*)d_in[15];
    float* out = (float*)d_out;

    char* ws = (char*)d_ws;
    const size_t NP = 400128;  // padded (N+1)*4 bytes
    float* dinv   = (float*)(ws);
    int*   rowptr = (int*)  (ws + NP);
    int*   bcnt   = (int*)  (ws + 2 * NP);
    int*   bbase  = (int*)  (ws + 2 * NP + 1024);
    int*   bcur   = (int*)  (ws + 2 * NP + 2048);
    int2*  rec    = (int2*) (ws + 2 * NP + 4096);
    unsigned short* Hh = (unsigned short*)(ws + 2 * NP + 4096 + (size_t)N_EDGES * 8);
    unsigned short* Ah = Hh + (size_t)N_NODES * DIM;
    unsigned short* Ch = Ah + (size_t)N_NODES * DIM;
    unsigned short* Wsw0 = Ch + (size_t)N_NODES * DIM;
    unsigned short* Wsw1 = Wsw0 + DIM * DIM;
    unsigned short* Wsw2 = Wsw1 + DIM * DIM;
    unsigned short* Wcsw = Wsw2 + DIM * DIM;   // 12*512 shorts
    int2*  tmp    = (int2*)Ch;                 // aliases Ch; dead before layer 0 writes Ch

    // ---- setup: swizzles + zero bcnt (1 dispatch) ----
    setup_misc<<<217, 256, 0, stream>>>(W[0], W[1], W[2], Wc, Wsw0, Wsw1, Wsw2, Wcsw, bcnt);

    // ---- CSR build (bucketed, no global per-node atomics) ----
    bhist<<<P1_GRID, 256, 0, stream>>>(ei, bcnt);
    bscan<<<1, 256, 0, stream>>>(bcnt, bbase, bcur);
    bucket_p1<<<P1_GRID, 256, 0, stream>>>(ei, bcur, tmp);
    bucket_p2a<<<NBUCK, 256, 0, stream>>>(tmp, bbase, rowptr, dinv);
    bucket_p2b<<<NBUCK, 256, 0, stream>>>(tmp, rowptr, dinv, rec);

    const int gemm_grid = (N_NODES + 127) / 128;  // 782
    const int agg_grid  = N_NODES / 4;            // 25000

    // layer 0: x fp32 -> Hh; agg -> Ch
    gemm_mfma_f<<<gemm_grid, 256, 0, stream>>>(x, Wsw0, Hh);
    agg_ln<<<agg_grid, 256, 0, stream>>>(Hh, nullptr, dinv, b[0], g[0], be[0], rowptr, rec, Ch);

    // layer 1: Ch -> Hh; agg (+resid Ch) -> Ah
    gemm_mfma_h<<<gemm_grid, 256, 0, stream>>>(Ch, Wsw1, Hh);
    agg_ln<<<agg_grid, 256, 0, stream>>>(Hh, Ch, dinv, b[1], g[1], be[1], rowptr, rec, Ah);

    // layer 2: Ah -> Hh; agg (+resid Ah) -> Ch
    gemm_mfma_h<<<gemm_grid, 256, 0, stream>>>(Ah, Wsw2, Hh);
    agg_ln<<<agg_grid, 256, 0, stream>>>(Hh, Ah, dinv, b[2], g[2], be[2], rowptr, rec, Ch);

    classifier_mfma<<<gemm_grid, 256, 0, stream>>>(Ch, Wcsw, bc, out);
}

// Round 14
// 425.484 us; speedup vs baseline: 1.2033x; 1.0350x over previous
//
#include <hip/hip_runtime.h>
#include <math.h>

#define N_NODES 100000
#define N_EDGES 1600000
#define DIM     128
#define NCLS    40
#define NBUCK   196      // ceil(100000/512) buckets of 512 nodes
#define P1_CH   4096     // edges per phase-1 block
#define P1_GRID 391      // ceil(1600000/4096)

typedef _Float16 f16x8 __attribute__((ext_vector_type(8)));
typedef _Float16 f16x2 __attribute__((ext_vector_type(2)));
typedef float    f32x4 __attribute__((ext_vector_type(4)));

__device__ inline unsigned short f16bits(float f) {
    union { _Float16 h; unsigned short u; } cv;
    cv.h = (_Float16)f;
    return cv.u;
}
__device__ inline f16x2 as_h2(unsigned u) {
    union { unsigned u; f16x2 h; } cv;
    cv.u = u;
    return cv.h;
}
__device__ inline unsigned as_u(f16x2 h) {
    union { f16x2 h; unsigned u; } cv;
    cv.h = h;
    return cv.u;
}
__device__ inline unsigned pack_h2(float lo, float hi) {
    f16x2 h;
    h.x = (_Float16)lo;
    h.y = (_Float16)hi;
    return as_u(h);
}

// ---------------------------------------------------------------- setup: W swizzles (f16 MFMA B-frag order) + zero bcnt
__global__ __launch_bounds__(256) void setup_misc(const float* __restrict__ W0,
                                                  const float* __restrict__ W1,
                                                  const float* __restrict__ W2,
                                                  const float* __restrict__ Wc,
                                                  unsigned short* __restrict__ Wsw0,
                                                  unsigned short* __restrict__ Wsw1,
                                                  unsigned short* __restrict__ Wsw2,
                                                  unsigned short* __restrict__ Wcsw,
                                                  int* __restrict__ bcnt) {
    int blk = blockIdx.x;
    if (blk < 192) {
        const float* W = (blk < 64) ? W0 : (blk < 128) ? W1 : W2;
        unsigned short* Wsw = (blk < 64) ? Wsw0 : (blk < 128) ? Wsw1 : Wsw2;
        int o = (blk & 63) * 256 + threadIdx.x;  // 0..16383
        int f = o >> 9;
        int l = (o >> 3) & 63;
        int j = o & 7;
        int n = f >> 2;
        int s = f & 3;
        int k = s * 32 + (l >> 4) * 8 + j;
        int c = (l & 15) * 8 + n;
        Wsw[o] = f16bits(W[k * DIM + c]);
    } else if (blk < 216) {
        int o = (blk - 192) * 256 + threadIdx.x; // 0..6143
        int f = o >> 9;
        int l = (o >> 3) & 63;
        int j = o & 7;
        int n = f >> 2;
        int s = f & 3;
        int k = s * 32 + (l >> 4) * 8 + j;
        int c = (l & 15) * 3 + n;
        Wcsw[o] = (c < NCLS) ? f16bits(Wc[k * NCLS + c]) : (unsigned short)0;
    } else {
        bcnt[threadIdx.x] = 0;
    }
}

// ---------------------------------------------------------------- bucket histogram (LDS) -> 196 global counters
__global__ __launch_bounds__(256) void bhist(const int* __restrict__ ei,
                                             int* __restrict__ bcnt) {
    __shared__ int h[256];
    const int t  = threadIdx.x;
    const int e0 = blockIdx.x * P1_CH;
    const int cnt = min(P1_CH, N_EDGES - e0);
    h[t] = 0;
    __syncthreads();
    for (int i = t; i < cnt; i += 256)
        atomicAdd(&h[ei[N_EDGES + e0 + i] >> 9], 1);
    __syncthreads();
    if (h[t]) atomicAdd(&bcnt[t], h[t]);
}

// ---------------------------------------------------------------- bucket scan (1 block): bbase (exclusive), bcur = bbase
__global__ __launch_bounds__(256) void bscan(const int* __restrict__ bcnt,
                                             int* __restrict__ bbase,
                                             int* __restrict__ bcur) {
    __shared__ int s[256];
    int t = threadIdx.x;
    s[t] = (t < NBUCK) ? bcnt[t] : 0;
    __syncthreads();
    for (int off = 1; off < 256; off <<= 1) {
        int x = (t >= off) ? s[t - off] : 0;
        __syncthreads();
        s[t] += x;
        __syncthreads();
    }
    int excl = (t == 0) ? 0 : s[t - 1];
    if (t < NBUCK) {
        bbase[t] = excl;
        bcur[t]  = excl;
    }
    if (t == 0) bbase[NBUCK] = N_EDGES;
}

// ---------------------------------------------------------------- phase 1: bucket edges by dst>>9 into tmp (coalesced runs)
__global__ __launch_bounds__(256) void bucket_p1(const int* __restrict__ ei,
                                                 int* __restrict__ bcur,
                                                 int2* __restrict__ tmp) {
    __shared__ int  hist[256];
    __shared__ int  lscan[256];
    __shared__ int  rank[256];
    __shared__ int  gbase[256];
    __shared__ int2 stage[P1_CH];      // 32 KB
    const int t  = threadIdx.x;
    const int e0 = blockIdx.x * P1_CH;
    const int cnt = min(P1_CH, N_EDGES - e0);

    hist[t] = 0;
    __syncthreads();

    int2 ed[16];
#pragma unroll
    for (int i = 0; i < 16; ++i) {
        int idx = t + i * 256;
        if (idx < cnt) {
            int s = ei[e0 + idx];
            int d = ei[N_EDGES + e0 + idx];
            ed[i] = make_int2(s, d);
            atomicAdd(&hist[d >> 9], 1);
        }
    }
    __syncthreads();

    int hv = hist[t];
    lscan[t] = hv;
    __syncthreads();
    for (int off = 1; off < 256; off <<= 1) {
        int x = (t >= off) ? lscan[t - off] : 0;
        __syncthreads();
        lscan[t] += x;
        __syncthreads();
    }
    int excl = (t == 0) ? 0 : lscan[t - 1];
    __syncthreads();
    lscan[t] = excl;
    rank[t]  = excl;
    if (hv > 0) gbase[t] = atomicAdd(&bcur[t], hv);
    __syncthreads();

#pragma unroll
    for (int i = 0; i < 16; ++i) {
        int idx = t + i * 256;
        if (idx < cnt) {
            int b = ed[i].y >> 9;
            int p = atomicAdd(&rank[b], 1);
            stage[p] = ed[i];
        }
    }
    __syncthreads();

    for (int p = t; p < cnt; p += 256) {
        int2 v = stage[p];
        int b = v.y >> 9;
        tmp[gbase[b] + (p - lscan[b])] = v;
    }
}

// ---------------------------------------------------------------- phase 2a: per-bucket node counts (LDS) -> rowptr + dinv
__global__ __launch_bounds__(256) void bucket_p2a(const int2* __restrict__ tmp,
                                                  const int* __restrict__ bbase,
                                                  int* __restrict__ rowptr,
                                                  float* __restrict__ dinv) {
    __shared__ int cnt[512];
    __shared__ int pscan[256];
    const int t  = threadIdx.x;
    const int b  = blockIdx.x;
    const int d0 = b << 9;
    const int dend = min(d0 + 512, N_NODES);
    const int nn = dend - d0;

    cnt[t] = 0;
    cnt[t + 256] = 0;
    __syncthreads();

    const int beg = bbase[b];
    const int end = bbase[b + 1];
    for (int idx = beg + t; idx < end; idx += 256)
        atomicAdd(&cnt[tmp[idx].y - d0], 1);
    __syncthreads();

    int c0 = cnt[2 * t];
    int c1 = cnt[2 * t + 1];
    pscan[t] = c0 + c1;
    __syncthreads();
    for (int off = 1; off < 256; off <<= 1) {
        int x = (t >= off) ? pscan[t - off] : 0;
        __syncthreads();
        pscan[t] += x;
        __syncthreads();
    }
    int excl = (t == 0) ? 0 : pscan[t - 1];
    if (2 * t < nn) {
        rowptr[d0 + 2 * t] = beg + excl;
        dinv[d0 + 2 * t]   = rsqrtf((float)c0 + 1.0f);
    }
    if (2 * t + 1 < nn) {
        rowptr[d0 + 2 * t + 1] = beg + excl + c0;
        dinv[d0 + 2 * t + 1]   = rsqrtf((float)c1 + 1.0f);
    }
    if (b == NBUCK - 1 && t == 0) rowptr[N_NODES] = N_EDGES;
}

// ---------------------------------------------------------------- phase 2b: within-bucket scatter; rec = (src*256, half2(w,w))
__global__ __launch_bounds__(256) void bucket_p2b(const int2* __restrict__ tmp,
                                                  const int* __restrict__ rowptr,
                                                  const float* __restrict__ dinv,
                                                  int2* __restrict__ rec) {
    __shared__ int cur[512];
    const int t  = threadIdx.x;
    const int b  = blockIdx.x;
    const int d0 = b << 9;
    const int dend = min(d0 + 512, N_NODES);
    const int nn = dend - d0;

    for (int i = t; i < nn; i += 256) cur[i] = rowptr[d0 + i];
    __syncthreads();

    const int beg = rowptr[d0];
    const int end = rowptr[dend];
    for (int idx = beg + t; idx < end; idx += 256) {
        int2 v = tmp[idx];
        int s = v.x, d = v.y;
        int pos = atomicAdd(&cur[d - d0], 1);
        unsigned short wb = f16bits(dinv[s] * dinv[d]);
        rec[pos] = make_int2(s << 8, (int)((unsigned)wb | ((unsigned)wb << 16)));
    }
}

// ---------------------------------------------------------------- MFMA GEMM, fp32 input (layer 0): 32 rows/wave, W via LDS
__global__ __launch_bounds__(256, 2) void gemm_mfma_f(const float* __restrict__ X,
                                                      const unsigned short* __restrict__ Wsw,
                                                      unsigned short* __restrict__ H) {
    __shared__ unsigned short wlds[32 * 512];   // 32 KB
    const int tid   = threadIdx.x;
    const int lane  = tid & 63;
    const int wave  = tid >> 6;
    const int row0w = blockIdx.x * 128 + wave * 32;
    const int m = lane & 15;
    const int q = lane >> 4;

    {
        const uint4* srcp = (const uint4*)Wsw;
        uint4*       dstp = (uint4*)wlds;
#pragma unroll
        for (int i = 0; i < 8; ++i) dstp[tid + i * 256] = srcp[tid + i * 256];
    }
    __syncthreads();

    f16x8 wf[32];
#pragma unroll
    for (int f = 0; f < 32; ++f)
        wf[f] = *(const f16x8*)(wlds + (f << 9) + lane * 8);

    f16x8 af[2][4];
#pragma unroll
    for (int ggr = 0; ggr < 2; ++ggr) {
        int r = row0w + ggr * 16 + m;
        if (r >= N_NODES) r = N_NODES - 1;
        const float* xp = X + (size_t)r * DIM + q * 8;
#pragma unroll
        for (int s = 0; s < 4; ++s) {
            float4 x0 = *(const float4*)(xp + s * 32);
            float4 x1 = *(const float4*)(xp + s * 32 + 4);
            f16x8 v;
            v[0] = (_Float16)x0.x; v[1] = (_Float16)x0.y;
            v[2] = (_Float16)x0.z; v[3] = (_Float16)x0.w;
            v[4] = (_Float16)x1.x; v[5] = (_Float16)x1.y;
            v[6] = (_Float16)x1.z; v[7] = (_Float16)x1.w;
            af[ggr][s] = v;
        }
    }

    f32x4 acc[2][8];
    f32x4 z = {0.f, 0.f, 0.f, 0.f};
#pragma unroll
    for (int ggr = 0; ggr < 2; ++ggr)
#pragma unroll
        for (int n = 0; n < 8; ++n) acc[ggr][n] = z;

#pragma unroll
    for (int s = 0; s < 4; ++s)
#pragma unroll
        for (int n = 0; n < 8; ++n) {
            acc[0][n] = __builtin_amdgcn_mfma_f32_16x16x32_f16(af[0][s], wf[n * 4 + s], acc[0][n], 0, 0, 0);
            acc[1][n] = __builtin_amdgcn_mfma_f32_16x16x32_f16(af[1][s], wf[n * 4 + s], acc[1][n], 0, 0, 0);
        }

#pragma unroll
    for (int ggr = 0; ggr < 2; ++ggr)
#pragma unroll
        for (int j = 0; j < 4; ++j) {
            int row = row0w + ggr * 16 + q * 4 + j;
            if (row < N_NODES) {
                uint4 o;
                o.x = pack_h2(acc[ggr][0][j], acc[ggr][1][j]);
                o.y = pack_h2(acc[ggr][2][j], acc[ggr][3][j]);
                o.z = pack_h2(acc[ggr][4][j], acc[ggr][5][j]);
                o.w = pack_h2(acc[ggr][6][j], acc[ggr][7][j]);
                *(uint4*)(H + (size_t)row * DIM + m * 8) = o;
            }
        }
}

// ---------------------------------------------------------------- MFMA GEMM, f16 input (layers 1,2): 32 rows/wave, W via LDS
__global__ __launch_bounds__(256, 2) void gemm_mfma_h(const unsigned short* __restrict__ Xh,
                                                      const unsigned short* __restrict__ Wsw,
                                                      unsigned short* __restrict__ H) {
    __shared__ unsigned short wlds[32 * 512];   // 32 KB
    const int tid   = threadIdx.x;
    const int lane  = tid & 63;
    const int wave  = tid >> 6;
    const int row0w = blockIdx.x * 128 + wave * 32;
    const int m = lane & 15;
    const int q = lane >> 4;

    {
        const uint4* srcp = (const uint4*)Wsw;
        uint4*       dstp = (uint4*)wlds;
#pragma unroll
        for (int i = 0; i < 8; ++i) dstp[tid + i * 256] = srcp[tid + i * 256];
    }
    __syncthreads();

    f16x8 wf[32];
#pragma unroll
    for (int f = 0; f < 32; ++f)
        wf[f] = *(const f16x8*)(wlds + (f << 9) + lane * 8);

    f16x8 af[2][4];
#pragma unroll
    for (int ggr = 0; ggr < 2; ++ggr) {
        int r = row0w + ggr * 16 + m;
        if (r >= N_NODES) r = N_NODES - 1;
        const unsigned short* xp = Xh + (size_t)r * DIM + q * 8;
#pragma unroll
        for (int s = 0; s < 4; ++s) af[ggr][s] = *(const f16x8*)(xp + s * 32);
    }

    f32x4 acc[2][8];
    f32x4 z = {0.f, 0.f, 0.f, 0.f};
#pragma unroll
    for (int ggr = 0; ggr < 2; ++ggr)
#pragma unroll
        for (int n = 0; n < 8; ++n) acc[ggr][n] = z;

#pragma unroll
    for (int s = 0; s < 4; ++s)
#pragma unroll
        for (int n = 0; n < 8; ++n) {
            acc[0][n] = __builtin_amdgcn_mfma_f32_16x16x32_f16(af[0][s], wf[n * 4 + s], acc[0][n], 0, 0, 0);
            acc[1][n] = __builtin_amdgcn_mfma_f32_16x16x32_f16(af[1][s], wf[n * 4 + s], acc[1][n], 0, 0, 0);
        }

#pragma unroll
    for (int ggr = 0; ggr < 2; ++ggr)
#pragma unroll
        for (int j = 0; j < 4; ++j) {
            int row = row0w + ggr * 16 + q * 4 + j;
            if (row < N_NODES) {
                uint4 o;
                o.x = pack_h2(acc[ggr][0][j], acc[ggr][1][j]);
                o.y = pack_h2(acc[ggr][2][j], acc[ggr][3][j]);
                o.z = pack_h2(acc[ggr][4][j], acc[ggr][5][j]);
                o.w = pack_h2(acc[ggr][6][j], acc[ggr][7][j]);
                *(uint4*)(H + (size_t)row * DIM + m * 8) = o;
            }
        }
}

// ---------------------------------------------------------------- fused gather-aggregate + LN + ELU (+ residual), f16
__global__ __launch_bounds__(256) void agg_ln(const unsigned short* __restrict__ Hh,
                                              const unsigned short* __restrict__ xin,
                                              const float* __restrict__ dinv,
                                              const float* __restrict__ bias,
                                              const float* __restrict__ g,
                                              const float* __restrict__ be,
                                              const int* __restrict__ rowptr,
                                              const int2* __restrict__ rec,
                                              unsigned short* __restrict__ outb) {
    int node = blockIdx.x * 4 + (threadIdx.x >> 6);
    int lane = threadIdx.x & 63;
    int sub  = lane & 15;
    int qtr  = lane >> 4;
    int beg = rowptr[node];
    int end = rowptr[node + 1];
    const char* Hb8 = (const char*)Hh;
    const unsigned laneoff = (unsigned)sub * 16;   // byte offset within row

    f16x2 acc[4];
    f16x2 hz = {(_Float16)0.f, (_Float16)0.f};
#pragma unroll
    for (int k = 0; k < 4; ++k) acc[k] = hz;

    for (int e0 = beg; e0 < end; e0 += 64) {
        int cnt = min(end - e0, 64);
        int2 rc = (lane < cnt) ? rec[e0 + lane] : make_int2(0, 0);
        int sv = rc.x;                        // src*256 byte offset (pads have w=0)
        int wv = rc.y;                        // packed half2 (w,w)
        int cntR = (cnt + 15) & ~15;
        for (int j = 0; j < cntR; j += 16) {
            int i0 = j + qtr, i1 = j + 4 + qtr, i2 = j + 8 + qtr, i3 = j + 12 + qtr;
            unsigned o0 = (unsigned)__shfl(sv, i0, 64) + laneoff;
            int      w0 = __shfl(wv, i0, 64);
            unsigned o1 = (unsigned)__shfl(sv, i1, 64) + laneoff;
            int      w1 = __shfl(wv, i1, 64);
            unsigned o2 = (unsigned)__shfl(sv, i2, 64) + laneoff;
            int      w2 = __shfl(wv, i2, 64);
            unsigned o3 = (unsigned)__shfl(sv, i3, 64) + laneoff;
            int      w3 = __shfl(wv, i3, 64);
            uint4 u0 = *(const uint4*)(Hb8 + o0);
            uint4 u1 = *(const uint4*)(Hb8 + o1);
            uint4 u2 = *(const uint4*)(Hb8 + o2);
            uint4 u3 = *(const uint4*)(Hb8 + o3);
            f16x2 hw0 = as_h2(w0), hw1 = as_h2(w1), hw2 = as_h2(w2), hw3 = as_h2(w3);
            acc[0] += as_h2(u0.x) * hw0;
            acc[1] += as_h2(u0.y) * hw0;
            acc[2] += as_h2(u0.z) * hw0;
            acc[3] += as_h2(u0.w) * hw0;
            acc[0] += as_h2(u1.x) * hw1;
            acc[1] += as_h2(u1.y) * hw1;
            acc[2] += as_h2(u1.z) * hw1;
            acc[3] += as_h2(u1.w) * hw1;
            acc[0] += as_h2(u2.x) * hw2;
            acc[1] += as_h2(u2.y) * hw2;
            acc[2] += as_h2(u2.z) * hw2;
            acc[3] += as_h2(u2.w) * hw2;
            acc[0] += as_h2(u3.x) * hw3;
            acc[1] += as_h2(u3.y) * hw3;
            acc[2] += as_h2(u3.z) * hw3;
            acc[3] += as_h2(u3.w) * hw3;
        }
    }

#pragma unroll
    for (int k = 0; k < 4; ++k) {
        acc[k] += as_h2(__shfl_xor(as_u(acc[k]), 16, 64));
        acc[k] += as_h2(__shfl_xor(as_u(acc[k]), 32, 64));
    }

    unsigned mu = as_u(acc[0]);
    mu = (qtr == 1) ? as_u(acc[1]) : mu;
    mu = (qtr == 2) ? as_u(acc[2]) : mu;
    mu = (qtr == 3) ? as_u(acc[3]) : mu;
    f16x2 mine = as_h2(mu);
    const int c0 = sub * 8 + qtr * 2;
    const unsigned nodeoff = ((unsigned)node << 8) + (unsigned)c0 * 2;

    float dv = dinv[node];
    float d2 = dv * dv;
    f16x2 hh = as_h2(*(const unsigned*)(Hb8 + nodeoff));
    float2 bb = *(const float2*)(bias + c0);
    float a0 = (float)mine.x + (float)hh.x * d2 + bb.x;
    float a1 = (float)mine.y + (float)hh.y * d2 + bb.y;

    float s1 = a0 + a1;
    float s2 = a0 * a0 + a1 * a1;
#pragma unroll
    for (int mk = 1; mk <= 32; mk <<= 1) {
        s1 += __shfl_xor(s1, mk, 64);
        s2 += __shfl_xor(s2, mk, 64);
    }
    float mean = s1 * (1.0f / 128.0f);
    float var  = s2 * (1.0f / 128.0f) - mean * mean;
    float rr   = rsqrtf(var + 1e-5f);
    float2 gg = *(const float2*)(g + c0);
    float2 ee = *(const float2*)(be + c0);
    float r0 = (a0 - mean) * rr * gg.x + ee.x;
    float r1 = (a1 - mean) * rr * gg.y + ee.y;
    r0 = r0 > 0.0f ? r0 : expm1f(r0);
    r1 = r1 > 0.0f ? r1 : expm1f(r1);
    if (xin) {
        f16x2 xi = as_h2(*(const unsigned*)((const char*)xin + nodeoff));
        r0 += (float)xi.x;
        r1 += (float)xi.y;
    }
    *(unsigned*)((char*)outb + nodeoff) = pack_h2(r0, r1);
}

// ---------------------------------------------------------------- MFMA classifier, f16 input: 32 rows/wave, Wc via LDS
__global__ __launch_bounds__(256) void classifier_mfma(const unsigned short* __restrict__ Xh,
                                                       const unsigned short* __restrict__ Wcsw,
                                                       const float* __restrict__ bc,
                                                       float* __restrict__ out) {
    __shared__ unsigned short wlds[12 * 512];   // 12 KB
    const int tid   = threadIdx.x;
    const int lane  = tid & 63;
    const int wave  = tid >> 6;
    const int row0w = blockIdx.x * 128 + wave * 32;
    const int m = lane & 15;
    const int q = lane >> 4;

    {
        const uint4* srcp = (const uint4*)Wcsw;
        uint4*       dstp = (uint4*)wlds;
#pragma unroll
        for (int i = 0; i < 3; ++i) dstp[tid + i * 256] = srcp[tid + i * 256];
    }
    __syncthreads();

    f16x8 wf[12];
#pragma unroll
    for (int f = 0; f < 12; ++f)
        wf[f] = *(const f16x8*)(wlds + (f << 9) + lane * 8);

    f16x8 af[2][4];
#pragma unroll
    for (int ggr = 0; ggr < 2; ++ggr) {
        int r = row0w + ggr * 16 + m;
        if (r >= N_NODES) r = N_NODES - 1;
        const unsigned short* xp = Xh + (size_t)r * DIM + q * 8;
#pragma unroll
        for (int s = 0; s < 4; ++s) af[ggr][s] = *(const f16x8*)(xp + s * 32);
    }

    f32x4 acc[2][3];
    f32x4 z = {0.f, 0.f, 0.f, 0.f};
#pragma unroll
    for (int ggr = 0; ggr < 2; ++ggr)
#pragma unroll
        for (int n = 0; n < 3; ++n) acc[ggr][n] = z;

#pragma unroll
    for (int s = 0; s < 4; ++s)
#pragma unroll
        for (int n = 0; n < 3; ++n) {
            acc[0][n] = __builtin_amdgcn_mfma_f32_16x16x32_f16(af[0][s], wf[n * 4 + s], acc[0][n], 0, 0, 0);
            acc[1][n] = __builtin_amdgcn_mfma_f32_16x16x32_f16(af[1][s], wf[n * 4 + s], acc[1][n], 0, 0, 0);
        }

    float bcv[3];
#pragma unroll
    for (int n = 0; n < 3; ++n) {
        int c = 3 * m + n;
        bcv[n] = (c < NCLS) ? bc[c] : 0.f;
    }

#pragma unroll
    for (int ggr = 0; ggr < 2; ++ggr)
#pragma unroll
        for (int j = 0; j < 4; ++j) {
            int row = row0w + ggr * 16 + q * 4 + j;
            if (row < N_NODES) {
#pragma unroll
                for (int n = 0; n < 3; ++n) {
                    int c = 3 * m + n;
                    if (c < NCLS)
                        out[(size_t)row * NCLS + c] = acc[ggr][n][j] + bcv[n];
                }
            }
        }
}

// ---------------------------------------------------------------- launch
extern "C" void kernel_launch(void* const* d_in, const int* in_sizes, int n_in,
                              void* d_out, int out_size, void* d_ws, size_t ws_size,
                              hipStream_t stream) {
    const float* x  = (const float*)d_in[0];
    const int*   ei = (const int*)d_in[1];
    const float* W[3]  = {(const float*)d_in[2], (const float*)d_in[6], (const float*)d_in[10]};
    const float* b[3]  = {(const float*)d_in[3], (const float*)d_in[7], (const float*)d_in[11]};
    const float* g[3]  = {(const float*)d_in[4], (const float*)d_in[8], (const float*)d_in[12]};
    const float* be[3] = {(const float*)d_in[5], (const float*)d_in[9], (const float*)d_in[13]};
    const float* Wc = (const float*)d_in[14];
    const float* bc = (const float*)d_in[15];
    float* out = (float*)d_out;

    char* ws = (char*)d_ws;
    const size_t NP = 400128;  // padded (N+1)*4 bytes
    float* dinv   = (float*)(ws);
    int*   rowptr = (int*)  (ws + NP);
    int*   bcnt   = (int*)  (ws + 2 * NP);
    int*   bbase  = (int*)  (ws + 2 * NP + 1024);
    int*   bcur   = (int*)  (ws + 2 * NP + 2048);
    int2*  rec    = (int2*) (ws + 2 * NP + 4096);
    unsigned short* Hh = (unsigned short*)(ws + 2 * NP + 4096 + (size_t)N_EDGES * 8);
    unsigned short* Ah = Hh + (size_t)N_NODES * DIM;
    unsigned short* Ch = Ah + (size_t)N_NODES * DIM;
    unsigned short* Wsw0 = Ch + (size_t)N_NODES * DIM;
    unsigned short* Wsw1 = Wsw0 + DIM * DIM;
    unsigned short* Wsw2 = Wsw1 + DIM * DIM;
    unsigned short* Wcsw = Wsw2 + DIM * DIM;   // 12*512 shorts
    int2*  tmp    = (int2*)Ch;                 // aliases Ch; dead before layer 0 writes Ch

    // ---- setup: swizzles + zero bcnt (1 dispatch) ----
    setup_misc<<<217, 256, 0, stream>>>(W[0], W[1], W[2], Wc, Wsw0, Wsw1, Wsw2, Wcsw, bcnt);

    // ---- CSR build (bucketed, no global per-node atomics) ----
    bhist<<<P1_GRID, 256, 0, stream>>>(ei, bcnt);
    bscan<<<1, 256, 0, stream>>>(bcnt, bbase, bcur);
    bucket_p1<<<P1_GRID, 256, 0, stream>>>(ei, bcur, tmp);
    bucket_p2a<<<NBUCK, 256, 0, stream>>>(tmp, bbase, rowptr, dinv);
    bucket_p2b<<<NBUCK, 256, 0, stream>>>(tmp, rowptr, dinv, rec);

    const int gemm_grid = (N_NODES + 127) / 128;  // 782
    const int agg_grid  = N_NODES / 4;            // 25000

    // layer 0: x fp32 -> Hh; agg -> Ch
    gemm_mfma_f<<<gemm_grid, 256, 0, stream>>>(x, Wsw0, Hh);
    agg_ln<<<agg_grid, 256, 0, stream>>>(Hh, nullptr, dinv, b[0], g[0], be[0], rowptr, rec, Ch);

    // layer 1: Ch -> Hh; agg (+resid Ch) -> Ah
    gemm_mfma_h<<<gemm_grid, 256, 0, stream>>>(Ch, Wsw1, Hh);
    agg_ln<<<agg_grid, 256, 0, stream>>>(Hh, Ch, dinv, b[1], g[1], be[1], rowptr, rec, Ah);

    // layer 2: Ah -> Hh; agg (+resid Ah) -> Ch
    gemm_mfma_h<<<gemm_grid, 256, 0, stream>>>(Ah, Wsw2, Hh);
    agg_ln<<<agg_grid, 256, 0, stream>>>(Hh, Ah, dinv, b[2], g[2], be[2], rowptr, rec, Ch);

    classifier_mfma<<<gemm_grid, 256, 0, stream>>>(Ch, Wcsw, bc, out);
}